// Round 1
// baseline (632.821 us; speedup 1.0000x reference)
//
#include <hip/hip_runtime.h>

typedef unsigned short ushort_t;

#define NORMC 0.35355339059327373f   // 64^-0.25
#define DIAGC 0.0625f                // 0.5 * 64^-0.5
#define RATIO 0.0625f                // 256^-0.5
#define KEPS  1e-4f
#define AEPS  1e-6f

__device__ __forceinline__ unsigned short f2bf(float f){
  unsigned u = __float_as_uint(f);
  unsigned r = (u + 0x7FFFu + ((u >> 16) & 1u)) >> 16;  // RNE
  return (unsigned short)r;
}
__device__ __forceinline__ float bf2f(unsigned short h){
  return __uint_as_float(((unsigned)h) << 16);
}
// order-preserving float<->uint for atomicMax over signed floats
__device__ __forceinline__ unsigned enc_f(float f){
  unsigned u = __float_as_uint(f);
  return (u & 0x80000000u) ? ~u : (u | 0x80000000u);
}
__device__ __forceinline__ float dec_f(unsigned e){
  unsigned b = (e & 0x80000000u) ? (e ^ 0x80000000u) : ~e;
  return __uint_as_float(b);
}

// K0: projT[d][m] = NORMC * proj[m][d]; init global-max slot
__global__ void k_prep(const float* __restrict__ proj, float* __restrict__ projT,
                       unsigned* __restrict__ kmax){
  int t = threadIdx.x;
  if (t == 0) *kmax = 0u;
  for (int d = 0; d < 64; ++d) projT[d*256 + t] = NORMC * proj[t*64 + d];
}

// K1/K2: dash GEMM [128 rows x 256 m], K=64 in two 32-tiles.
// pass=0: blocks 0..511 = q rows (rowmax, store qf); blocks 512..1023 = k rows (global max only)
// pass=1: k rows, store kf using global max
__launch_bounds__(256)
__global__ void k_feat(const float* __restrict__ q, const float* __restrict__ k,
                       const float* __restrict__ projT,
                       ushort_t* __restrict__ qf, ushort_t* __restrict__ kf,
                       unsigned* __restrict__ kmax, int pass)
{
  __shared__ float pt[32*256];   // projT k-tile [32][256]
  __shared__ float xt[128*33];   // data tile [128][32] (+1 pad)
  __shared__ float wred[4];
  int tid = threadIdx.x;
  int mode, tile;
  if (pass == 0){
    if (blockIdx.x < 512){ mode = 0; tile = (int)blockIdx.x; }
    else                 { mode = 1; tile = (int)blockIdx.x - 512; }
  } else { mode = 2; tile = (int)blockIdx.x; }
  const float* src = (mode == 0) ? q : k;
  int row0 = tile * 128;
  int tx = tid & 15, ty = tid >> 4;

  float acc[8][16];
  #pragma unroll
  for (int r=0;r<8;++r){
    #pragma unroll
    for (int j=0;j<16;++j) acc[r][j]=0.f;
  }
  float dsum[8];
  #pragma unroll
  for (int r=0;r<8;++r) dsum[r]=0.f;

  for (int k0=0;k0<64;k0+=32){
    __syncthreads();
    for (int i=tid;i<32*256;i+=256) pt[i] = projT[k0*256 + i];
    for (int i=tid;i<128*32;i+=256){ int r=i>>5, d=i&31; xt[r*33+d] = src[(size_t)(row0+r)*64 + k0 + d]; }
    __syncthreads();
    // diag partials: this tile's d = tx*2, tx*2+1
    #pragma unroll
    for (int r=0;r<8;++r){
      float x0 = xt[(ty*8+r)*33 + tx*2];
      float x1 = xt[(ty*8+r)*33 + tx*2 + 1];
      dsum[r] += x0*x0 + x1*x1;
    }
    for (int kk=0;kk<32;++kk){
      float a[8];
      #pragma unroll
      for (int r=0;r<8;++r) a[r] = xt[(ty*8+r)*33 + kk];
      const float4* pp = (const float4*)&pt[kk*256 + tx*16];
      #pragma unroll
      for (int jq=0;jq<4;++jq){
        float4 pv = pp[jq];
        #pragma unroll
        for (int r=0;r<8;++r){
          acc[r][jq*4+0] += a[r]*pv.x;
          acc[r][jq*4+1] += a[r]*pv.y;
          acc[r][jq*4+2] += a[r]*pv.z;
          acc[r][jq*4+3] += a[r]*pv.w;
        }
      }
    }
  }
  // per-row reductions across the 16 lanes sharing ty (width-16 butterfly)
  float rmax[8];
  #pragma unroll
  for (int r=0;r<8;++r){
    float mx = acc[r][0];
    #pragma unroll
    for (int j=1;j<16;++j) mx = fmaxf(mx, acc[r][j]);
    #pragma unroll
    for (int s=1;s<16;s<<=1) mx = fmaxf(mx, __shfl_xor(mx, s, 16));
    rmax[r] = mx;
    #pragma unroll
    for (int s=1;s<16;s<<=1) dsum[r] += __shfl_xor(dsum[r], s, 16);
  }

  if (mode == 1){
    float wm = rmax[0];
    #pragma unroll
    for (int r=1;r<8;++r) wm = fmaxf(wm, rmax[r]);
    wm = fmaxf(wm, __shfl_xor(wm, 16, 64));
    wm = fmaxf(wm, __shfl_xor(wm, 32, 64));
    if ((tid & 63) == 0) wred[tid>>6] = wm;
    __syncthreads();
    if (tid == 0){
      float m4 = fmaxf(fmaxf(wred[0],wred[1]), fmaxf(wred[2],wred[3]));
      atomicMax(kmax, enc_f(m4));
    }
    return;
  }
  float gm = 0.f;
  if (mode == 2) gm = dec_f(*kmax);
  ushort_t* dst = (mode==0) ? qf : kf;
  #pragma unroll
  for (int r=0;r<8;++r){
    float st = (mode==0) ? rmax[r] : gm;
    float dg = DIAGC * dsum[r];
    unsigned w[8];
    #pragma unroll
    for (int j2=0;j2<8;++j2){
      float v0 = RATIO * (__expf(acc[r][2*j2]   - dg - st) + KEPS);
      float v1 = RATIO * (__expf(acc[r][2*j2+1] - dg - st) + KEPS);
      w[j2] = (unsigned)f2bf(v0) | ((unsigned)f2bf(v1) << 16);
    }
    uint4* o = (uint4*)&dst[(size_t)(row0 + ty*8 + r)*256 + tx*16];
    o[0] = make_uint4(w[0],w[1],w[2],w[3]);
    o[1] = make_uint4(w[4],w[5],w[6],w[7]);
  }
}

// K3: per-chunk local sums. Zl[cb][m] = sum_c kf; Sl[cb][e][m] = sum_c kf[c,m]*v[c,e]
__launch_bounds__(256)
__global__ void k_chunk(const ushort_t* __restrict__ kf, const float* __restrict__ v,
                        float* __restrict__ Zl, float* __restrict__ Sl){
  __shared__ float vl[8][64];
  int tid = threadIdx.x;
  int bh = blockIdx.x >> 5, j = blockIdx.x & 31;
  int row0 = bh*4096 + j*128;
  float z = 0.f;
  float acc[64];
  #pragma unroll
  for (int e=0;e<64;++e) acc[e]=0.f;
  for (int c0=0;c0<128;c0+=8){
    __syncthreads();
    for (int i=tid;i<512;i+=256){ int c=i>>6, e=i&63; vl[c][e] = v[(size_t)(row0+c0+c)*64 + e]; }
    __syncthreads();
    for (int c=0;c<8;++c){
      float kv = bf2f(kf[(size_t)(row0+c0+c)*256 + tid]);
      z += kv;
      const float4* vp = (const float4*)vl[c];
      #pragma unroll
      for (int e4=0;e4<16;++e4){
        float4 vv = vp[e4];
        acc[e4*4+0]+=kv*vv.x; acc[e4*4+1]+=kv*vv.y; acc[e4*4+2]+=kv*vv.z; acc[e4*4+3]+=kv*vv.w;
      }
    }
  }
  int cb = bh*32 + j;
  Zl[(size_t)cb*256 + tid] = z;
  #pragma unroll
  for (int e=0;e<64;++e) Sl[(size_t)cb*16384 + (size_t)e*256 + tid] = acc[e];
}

// K4: per-(bh) exclusive prefix over 32 chunks (in place); inclusive totals -> Z,S outputs
__launch_bounds__(256)
__global__ void k_scan(float* __restrict__ Zl, float* __restrict__ Sl,
                       float* __restrict__ outZ, float* __restrict__ outS){
  int t = threadIdx.x; int bh = blockIdx.x;
  float rz = 0.f;
  for (int j=0;j<32;++j){
    size_t idx = (size_t)(bh*32+j)*256 + t;
    float x = Zl[idx]; Zl[idx] = rz; rz += x;
  }
  outZ[(size_t)bh*256 + t] = rz;
  float rs[64];
  #pragma unroll
  for (int i=0;i<64;++i) rs[i]=0.f;
  for (int j=0;j<32;++j){
    size_t base = (size_t)(bh*32+j)*16384;
    #pragma unroll
    for (int i=0;i<64;++i){
      size_t idx = base + (size_t)i*256 + t;
      float x = Sl[idx]; Sl[idx] = rs[i]; rs[i] += x;
    }
  }
  // Sl layout [e][m]: i=e, t=m ; outS layout [m][e]
  #pragma unroll
  for (int i=0;i<64;++i) outS[(size_t)bh*16384 + (size_t)t*64 + i] = rs[i];
}

// K5: per-chunk output. A=qf*kf^T (masked, LDS), out = (A*v + qf*S0) / D
__launch_bounds__(256)
__global__ void k_out(const ushort_t* __restrict__ qf, const ushort_t* __restrict__ kf,
                      const float* __restrict__ v, const float* __restrict__ Zp,
                      const float* __restrict__ Sp, float* __restrict__ outO){
  extern __shared__ float sm[];
  float* A   = sm;            // [128][130] fp32
  float* qt  = sm + 16640;    // G1 [128][33]
  float* ktT = sm + 20864;    // G1 [32][132]
  float* vt  = sm + 16640;    // G2 [128][68]
  float* qft = sm + 25344;    // G2 [128][33]
  float* s0t = sm + 29568;    // G2 [32][68]
  float* z0  = sm + 31744;    // [256]
  float* dv  = sm + 32000;    // [128]
  int tid = threadIdx.x; int tx = tid & 15, ty = tid >> 4;
  int bh = blockIdx.x >> 5, j = blockIdx.x & 31;
  int row0 = bh*4096 + j*128;
  size_t qbase = (size_t)row0*256;
  int pb = bh*32 + j;

  // ---- G1: A = qf * kf^T over M=256 in 32-tiles ----
  float a1[8][8];
  #pragma unroll
  for (int r=0;r<8;++r){
    #pragma unroll
    for (int i=0;i<8;++i) a1[r][i]=0.f;
  }
  for (int m0=0;m0<256;m0+=32){
    __syncthreads();
    for (int i=tid;i<4096;i+=256){ int r=i>>5, d=i&31; qt[r*33+d]   = bf2f(qf[qbase + (size_t)r*256 + m0 + d]); }
    for (int i=tid;i<4096;i+=256){ int r=i>>5, d=i&31; ktT[d*132+r] = bf2f(kf[qbase + (size_t)r*256 + m0 + d]); }
    __syncthreads();
    for (int kk=0;kk<32;++kk){
      float a[8];
      #pragma unroll
      for (int r=0;r<8;++r) a[r] = qt[(ty*8+r)*33 + kk];
      const float4* bp = (const float4*)&ktT[kk*132 + tx*8];
      float4 b0 = bp[0], b1 = bp[1];
      #pragma unroll
      for (int r=0;r<8;++r){
        a1[r][0]+=a[r]*b0.x; a1[r][1]+=a[r]*b0.y; a1[r][2]+=a[r]*b0.z; a1[r][3]+=a[r]*b0.w;
        a1[r][4]+=a[r]*b1.x; a1[r][5]+=a[r]*b1.y; a1[r][6]+=a[r]*b1.z; a1[r][7]+=a[r]*b1.w;
      }
    }
  }
  // mask (i<=c inclusive) and write A
  #pragma unroll
  for (int r=0;r<8;++r){
    int c = ty*8+r;
    #pragma unroll
    for (int i=0;i<8;++i){
      int col = tx*8+i;
      A[c*130+col] = (col <= c) ? a1[r][i] : 0.f;
    }
  }
  __syncthreads();   // G1 LDS reads done; A visible after next sync
  // ---- G2 ----
  for (int i=tid;i<8192;i+=256){ int r=i>>6, e=i&63; vt[r*68+e] = v[(size_t)(row0+r)*64 + e]; }
  z0[tid] = Zp[(size_t)pb*256 + tid];
  __syncthreads();

  float a2[8][4];
  #pragma unroll
  for (int r=0;r<8;++r){
    #pragma unroll
    for (int e=0;e<4;++e) a2[r][e]=0.f;
  }
  // intra-chunk: A * v  (wave w only needs kk < 32*(w+1); A is zero above diagonal)
  int kkmax = ((tid >> 6) + 1) * 32;
  for (int kk=0;kk<kkmax;++kk){
    float a[8];
    #pragma unroll
    for (int r=0;r<8;++r) a[r] = A[(ty*8+r)*130 + kk];
    float4 vv = *(const float4*)&vt[kk*68 + tx*4];
    #pragma unroll
    for (int r=0;r<8;++r){ a2[r][0]+=a[r]*vv.x; a2[r][1]+=a[r]*vv.y; a2[r][2]+=a[r]*vv.z; a2[r][3]+=a[r]*vv.w; }
  }
  // inter-chunk: qf * S0 over M=256 in 32-tiles; also accumulate qf·(Z0+eps) per row
  float sQZ = 0.f;
  for (int m0=0;m0<256;m0+=32){
    __syncthreads();
    for (int i=tid;i<4096;i+=256){ int r=i>>5, d=i&31; qft[r*33+d] = bf2f(qf[qbase + (size_t)r*256 + m0 + d]); }
    for (int i=tid;i<2048;i+=256){ int mm=i&31, e=i>>5; s0t[mm*68+e] = Sp[(size_t)pb*16384 + (size_t)e*256 + m0 + mm]; }
    __syncthreads();
    for (int kk=0;kk<32;++kk){
      float a[8];
      #pragma unroll
      for (int r=0;r<8;++r) a[r] = qft[(ty*8+r)*33 + kk];
      float4 ss = *(const float4*)&s0t[kk*68 + tx*4];
      #pragma unroll
      for (int r=0;r<8;++r){ a2[r][0]+=a[r]*ss.x; a2[r][1]+=a[r]*ss.y; a2[r][2]+=a[r]*ss.z; a2[r][3]+=a[r]*ss.w; }
    }
    if (tid < 128){
      #pragma unroll
      for (int d=0;d<32;++d) sQZ += qft[tid*33+d] * (z0[m0+d] + AEPS);
    }
  }
  __syncthreads();
  if (tid < 128){
    float rsum = 0.f;
    for (int i=0;i<=tid;++i) rsum += A[tid*130+i];
    dv[tid] = 1.0f / (sQZ + rsum);
  }
  __syncthreads();
  #pragma unroll
  for (int r=0;r<8;++r){
    int c = ty*8+r;
    float di = dv[c];
    float4 o; o.x=a2[r][0]*di; o.y=a2[r][1]*di; o.z=a2[r][2]*di; o.w=a2[r][3]*di;
    *(float4*)&outO[(size_t)(row0 + c)*64 + tx*4] = o;
  }
}

extern "C" void kernel_launch(void* const* d_in, const int* in_sizes, int n_in,
                              void* d_out, int out_size, void* d_ws, size_t ws_size,
                              hipStream_t stream){
  (void)in_sizes; (void)n_in; (void)out_size; (void)ws_size;
  const float* q    = (const float*)d_in[0];
  const float* k    = (const float*)d_in[1];
  const float* v    = (const float*)d_in[2];
  const float* proj = (const float*)d_in[3];

  char* ws = (char*)d_ws;
  unsigned* kmax = (unsigned*)ws;                                   // 256 B slot
  float*    projT= (float*)(ws + 256);                              // 65536 B
  ushort_t* qf   = (ushort_t*)(ws + 65792);                         // 33554432 B
  ushort_t* kf   = (ushort_t*)(ws + 65792 + 33554432);              // 33554432 B
  float*    Zl   = (float*)(ws + 65792 + 67108864);                 // 524288 B
  float*    Sl   = (float*)(ws + 65792 + 67108864 + 524288);        // 33554432 B

  float* outO = (float*)d_out;
  float* outZ = outO + (size_t)2*8*4096*64;   // 4194304
  float* outS = outZ + 2*8*256;               // +4096

  hipFuncSetAttribute((const void*)k_out, hipFuncAttributeMaxDynamicSharedMemorySize, 131072);

  k_prep <<<1,    256, 0, stream>>>(proj, projT, kmax);
  k_feat <<<1024, 256, 0, stream>>>(q, k, projT, qf, kf, kmax, 0);
  k_feat <<<512,  256, 0, stream>>>(q, k, projT, qf, kf, kmax, 1);
  k_chunk<<<512,  256, 0, stream>>>(kf, v, Zl, Sl);
  k_scan <<<16,   256, 0, stream>>>(Zl, Sl, outZ, outS);
  k_out  <<<512,  256, 128512, stream>>>(qf, kf, v, Zl, Sl, outO);
}

// Round 2
// 370.725 us; speedup vs baseline: 1.7070x; 1.7070x over previous
//
#include <hip/hip_runtime.h>

typedef unsigned short ushort_t;

#define NORMC 0.35355339059327373f   // 64^-0.25
#define DIAGC 0.0625f                // 0.5 * 64^-0.5
#define RATIO 0.0625f                // 256^-0.5
#define KEPS  1e-4f
#define AEPS  1e-6f

__device__ __forceinline__ unsigned short f2bf(float f){
  unsigned u = __float_as_uint(f);
  unsigned r = (u + 0x7FFFu + ((u >> 16) & 1u)) >> 16;  // RNE
  return (unsigned short)r;
}
__device__ __forceinline__ float bf2f(unsigned short h){
  return __uint_as_float(((unsigned)h) << 16);
}
// order-preserving float<->uint for atomicMax over signed floats
__device__ __forceinline__ unsigned enc_f(float f){
  unsigned u = __float_as_uint(f);
  return (u & 0x80000000u) ? ~u : (u | 0x80000000u);
}
__device__ __forceinline__ float dec_f(unsigned e){
  unsigned b = (e & 0x80000000u) ? (e ^ 0x80000000u) : ~e;
  return __uint_as_float(b);
}

// K0: projT[d][m] = NORMC * proj[m][d]; init global-max slot
__global__ void k_prep(const float* __restrict__ proj, float* __restrict__ projT,
                       unsigned* __restrict__ kmax){
  int t = threadIdx.x;
  if (t == 0) *kmax = 0u;
  for (int d = 0; d < 64; ++d) projT[d*256 + t] = NORMC * proj[t*64 + d];
}

// K1/K2: dash GEMM [128 rows x 256 m], K=64 in two 32-tiles.
// pass=0: blocks 0..511 = q rows (rowmax, store qf); blocks 512..1023 = k rows (global max only)
// pass=1: k rows, store kf using global max
__launch_bounds__(256)
__global__ void k_feat(const float* __restrict__ q, const float* __restrict__ k,
                       const float* __restrict__ projT,
                       ushort_t* __restrict__ qf, ushort_t* __restrict__ kf,
                       unsigned* __restrict__ kmax, int pass)
{
  __shared__ float pt[32*256];   // projT k-tile [32][256]
  __shared__ float xt[128*33];   // data tile [128][32] (+1 pad)
  __shared__ float wred[4];
  int tid = threadIdx.x;
  int mode, tile;
  if (pass == 0){
    if (blockIdx.x < 512){ mode = 0; tile = (int)blockIdx.x; }
    else                 { mode = 1; tile = (int)blockIdx.x - 512; }
  } else { mode = 2; tile = (int)blockIdx.x; }
  const float* src = (mode == 0) ? q : k;
  int row0 = tile * 128;
  int tx = tid & 15, ty = tid >> 4;

  float acc[8][16];
  #pragma unroll
  for (int r=0;r<8;++r){
    #pragma unroll
    for (int j=0;j<16;++j) acc[r][j]=0.f;
  }
  float dsum[8];
  #pragma unroll
  for (int r=0;r<8;++r) dsum[r]=0.f;

  for (int k0=0;k0<64;k0+=32){
    __syncthreads();
    for (int i=tid;i<32*256;i+=256) pt[i] = projT[k0*256 + i];
    for (int i=tid;i<128*32;i+=256){ int r=i>>5, d=i&31; xt[r*33+d] = src[(size_t)(row0+r)*64 + k0 + d]; }
    __syncthreads();
    // diag partials: this tile's d = tx*2, tx*2+1
    #pragma unroll
    for (int r=0;r<8;++r){
      float x0 = xt[(ty*8+r)*33 + tx*2];
      float x1 = xt[(ty*8+r)*33 + tx*2 + 1];
      dsum[r] += x0*x0 + x1*x1;
    }
    for (int kk=0;kk<32;++kk){
      float a[8];
      #pragma unroll
      for (int r=0;r<8;++r) a[r] = xt[(ty*8+r)*33 + kk];
      const float4* pp = (const float4*)&pt[kk*256 + tx*16];
      #pragma unroll
      for (int jq=0;jq<4;++jq){
        float4 pv = pp[jq];
        #pragma unroll
        for (int r=0;r<8;++r){
          acc[r][jq*4+0] += a[r]*pv.x;
          acc[r][jq*4+1] += a[r]*pv.y;
          acc[r][jq*4+2] += a[r]*pv.z;
          acc[r][jq*4+3] += a[r]*pv.w;
        }
      }
    }
  }
  // per-row reductions across the 16 lanes sharing ty (width-16 butterfly)
  float rmax[8];
  #pragma unroll
  for (int r=0;r<8;++r){
    float mx = acc[r][0];
    #pragma unroll
    for (int j=1;j<16;++j) mx = fmaxf(mx, acc[r][j]);
    #pragma unroll
    for (int s=1;s<16;s<<=1) mx = fmaxf(mx, __shfl_xor(mx, s, 16));
    rmax[r] = mx;
    #pragma unroll
    for (int s=1;s<16;s<<=1) dsum[r] += __shfl_xor(dsum[r], s, 16);
  }

  if (mode == 1){
    float wm = rmax[0];
    #pragma unroll
    for (int r=1;r<8;++r) wm = fmaxf(wm, rmax[r]);
    wm = fmaxf(wm, __shfl_xor(wm, 16, 64));
    wm = fmaxf(wm, __shfl_xor(wm, 32, 64));
    if ((tid & 63) == 0) wred[tid>>6] = wm;
    __syncthreads();
    if (tid == 0){
      float m4 = fmaxf(fmaxf(wred[0],wred[1]), fmaxf(wred[2],wred[3]));
      atomicMax(kmax, enc_f(m4));
    }
    return;
  }
  float gm = 0.f;
  if (mode == 2) gm = dec_f(*kmax);
  ushort_t* dst = (mode==0) ? qf : kf;
  #pragma unroll
  for (int r=0;r<8;++r){
    float st = (mode==0) ? rmax[r] : gm;
    float dg = DIAGC * dsum[r];
    unsigned w[8];
    #pragma unroll
    for (int j2=0;j2<8;++j2){
      float v0 = RATIO * (__expf(acc[r][2*j2]   - dg - st) + KEPS);
      float v1 = RATIO * (__expf(acc[r][2*j2+1] - dg - st) + KEPS);
      w[j2] = (unsigned)f2bf(v0) | ((unsigned)f2bf(v1) << 16);
    }
    uint4* o = (uint4*)&dst[(size_t)(row0 + ty*8 + r)*256 + tx*16];
    o[0] = make_uint4(w[0],w[1],w[2],w[3]);
    o[1] = make_uint4(w[4],w[5],w[6],w[7]);
  }
}

// K3: per-chunk local sums. Zl[cb][m] = sum_c kf; Sl[cb][e][m] = sum_c kf[c,m]*v[c,e]
__launch_bounds__(256)
__global__ void k_chunk(const ushort_t* __restrict__ kf, const float* __restrict__ v,
                        float* __restrict__ Zl, float* __restrict__ Sl){
  __shared__ float vl[8][64];
  int tid = threadIdx.x;
  int bh = blockIdx.x >> 5, j = blockIdx.x & 31;
  int row0 = bh*4096 + j*128;
  float z = 0.f;
  float acc[64];
  #pragma unroll
  for (int e=0;e<64;++e) acc[e]=0.f;
  for (int c0=0;c0<128;c0+=8){
    __syncthreads();
    for (int i=tid;i<512;i+=256){ int c=i>>6, e=i&63; vl[c][e] = v[(size_t)(row0+c0+c)*64 + e]; }
    __syncthreads();
    for (int c=0;c<8;++c){
      float kv = bf2f(kf[(size_t)(row0+c0+c)*256 + tid]);
      z += kv;
      const float4* vp = (const float4*)vl[c];
      #pragma unroll
      for (int e4=0;e4<16;++e4){
        float4 vv = vp[e4];
        acc[e4*4+0]+=kv*vv.x; acc[e4*4+1]+=kv*vv.y; acc[e4*4+2]+=kv*vv.z; acc[e4*4+3]+=kv*vv.w;
      }
    }
  }
  int cb = bh*32 + j;
  Zl[(size_t)cb*256 + tid] = z;
  #pragma unroll
  for (int e=0;e<64;++e) Sl[(size_t)cb*16384 + (size_t)e*256 + tid] = acc[e];
}

// K4: parallel exclusive scan over the 32 chunks.
// grid = 16 * 65: s in [0,64): one (bh, e) slice of Sl; s == 64: the Zl slice.
// Each thread owns one m; 8-deep unroll batches independent loads for ILP.
__launch_bounds__(256)
__global__ void k_scan(float* __restrict__ Zl, float* __restrict__ Sl,
                       float* __restrict__ outZ, float* __restrict__ outS){
  int t = threadIdx.x;
  int bh = blockIdx.x / 65;
  int s  = blockIdx.x % 65;
  if (s == 64){
    size_t base = (size_t)(bh*32)*256 + t;
    float rz = 0.f;
    #pragma unroll
    for (int j0=0;j0<32;j0+=8){
      float x[8];
      #pragma unroll
      for (int u=0;u<8;++u) x[u] = Zl[base + (size_t)(j0+u)*256];
      #pragma unroll
      for (int u=0;u<8;++u){ Zl[base + (size_t)(j0+u)*256] = rz; rz += x[u]; }
    }
    outZ[(size_t)bh*256 + t] = rz;
  } else {
    int e = s;
    size_t base = (size_t)(bh*32)*16384 + (size_t)e*256 + t;
    float rs = 0.f;
    #pragma unroll
    for (int j0=0;j0<32;j0+=8){
      float x[8];
      #pragma unroll
      for (int u=0;u<8;++u) x[u] = Sl[base + (size_t)(j0+u)*16384];
      #pragma unroll
      for (int u=0;u<8;++u){ Sl[base + (size_t)(j0+u)*16384] = rs; rs += x[u]; }
    }
    // outS layout [bh][m][e]
    outS[(size_t)bh*16384 + (size_t)t*64 + e] = rs;
  }
}

// K5: per-chunk output. A=qf*kf^T (masked, LDS), out = (A*v + qf*S0) / D
__launch_bounds__(256)
__global__ void k_out(const ushort_t* __restrict__ qf, const ushort_t* __restrict__ kf,
                      const float* __restrict__ v, const float* __restrict__ Zp,
                      const float* __restrict__ Sp, float* __restrict__ outO){
  extern __shared__ float sm[];
  float* A   = sm;            // [128][130] fp32
  float* qt  = sm + 16640;    // G1 [128][33]
  float* ktT = sm + 20864;    // G1 [32][132]
  float* vt  = sm + 16640;    // G2 [128][68]
  float* qft = sm + 25344;    // G2 [128][33]
  float* s0t = sm + 29568;    // G2 [32][68]
  float* z0  = sm + 31744;    // [256]
  float* dv  = sm + 32000;    // [128]
  int tid = threadIdx.x; int tx = tid & 15, ty = tid >> 4;
  int bh = blockIdx.x >> 5, j = blockIdx.x & 31;
  int row0 = bh*4096 + j*128;
  size_t qbase = (size_t)row0*256;
  int pb = bh*32 + j;

  // ---- G1: A = qf * kf^T over M=256 in 32-tiles ----
  float a1[8][8];
  #pragma unroll
  for (int r=0;r<8;++r){
    #pragma unroll
    for (int i=0;i<8;++i) a1[r][i]=0.f;
  }
  for (int m0=0;m0<256;m0+=32){
    __syncthreads();
    for (int i=tid;i<4096;i+=256){ int r=i>>5, d=i&31; qt[r*33+d]   = bf2f(qf[qbase + (size_t)r*256 + m0 + d]); }
    for (int i=tid;i<4096;i+=256){ int r=i>>5, d=i&31; ktT[d*132+r] = bf2f(kf[qbase + (size_t)r*256 + m0 + d]); }
    __syncthreads();
    for (int kk=0;kk<32;++kk){
      float a[8];
      #pragma unroll
      for (int r=0;r<8;++r) a[r] = qt[(ty*8+r)*33 + kk];
      const float4* bp = (const float4*)&ktT[kk*132 + tx*8];
      float4 b0 = bp[0], b1 = bp[1];
      #pragma unroll
      for (int r=0;r<8;++r){
        a1[r][0]+=a[r]*b0.x; a1[r][1]+=a[r]*b0.y; a1[r][2]+=a[r]*b0.z; a1[r][3]+=a[r]*b0.w;
        a1[r][4]+=a[r]*b1.x; a1[r][5]+=a[r]*b1.y; a1[r][6]+=a[r]*b1.z; a1[r][7]+=a[r]*b1.w;
      }
    }
  }
  // mask (i<=c inclusive) and write A
  #pragma unroll
  for (int r=0;r<8;++r){
    int c = ty*8+r;
    #pragma unroll
    for (int i=0;i<8;++i){
      int col = tx*8+i;
      A[c*130+col] = (col <= c) ? a1[r][i] : 0.f;
    }
  }
  __syncthreads();   // G1 LDS reads done; A visible after next sync
  // ---- G2 ----
  for (int i=tid;i<8192;i+=256){ int r=i>>6, e=i&63; vt[r*68+e] = v[(size_t)(row0+r)*64 + e]; }
  z0[tid] = Zp[(size_t)pb*256 + tid];
  __syncthreads();

  float a2[8][4];
  #pragma unroll
  for (int r=0;r<8;++r){
    #pragma unroll
    for (int e=0;e<4;++e) a2[r][e]=0.f;
  }
  // intra-chunk: A * v  (wave w only needs kk < 32*(w+1); A is zero above diagonal)
  int kkmax = ((tid >> 6) + 1) * 32;
  for (int kk=0;kk<kkmax;++kk){
    float a[8];
    #pragma unroll
    for (int r=0;r<8;++r) a[r] = A[(ty*8+r)*130 + kk];
    float4 vv = *(const float4*)&vt[kk*68 + tx*4];
    #pragma unroll
    for (int r=0;r<8;++r){ a2[r][0]+=a[r]*vv.x; a2[r][1]+=a[r]*vv.y; a2[r][2]+=a[r]*vv.z; a2[r][3]+=a[r]*vv.w; }
  }
  // inter-chunk: qf * S0 over M=256 in 32-tiles; also accumulate qf·(Z0+eps) per row
  float sQZ = 0.f;
  for (int m0=0;m0<256;m0+=32){
    __syncthreads();
    for (int i=tid;i<4096;i+=256){ int r=i>>5, d=i&31; qft[r*33+d] = bf2f(qf[qbase + (size_t)r*256 + m0 + d]); }
    for (int i=tid;i<2048;i+=256){ int mm=i&31, e=i>>5; s0t[mm*68+e] = Sp[(size_t)pb*16384 + (size_t)e*256 + m0 + mm]; }
    __syncthreads();
    for (int kk=0;kk<32;++kk){
      float a[8];
      #pragma unroll
      for (int r=0;r<8;++r) a[r] = qft[(ty*8+r)*33 + kk];
      float4 ss = *(const float4*)&s0t[kk*68 + tx*4];
      #pragma unroll
      for (int r=0;r<8;++r){ a2[r][0]+=a[r]*ss.x; a2[r][1]+=a[r]*ss.y; a2[r][2]+=a[r]*ss.z; a2[r][3]+=a[r]*ss.w; }
    }
    if (tid < 128){
      #pragma unroll
      for (int d=0;d<32;++d) sQZ += qft[tid*33+d] * (z0[m0+d] + AEPS);
    }
  }
  __syncthreads();
  if (tid < 128){
    float rsum = 0.f;
    for (int i=0;i<=tid;++i) rsum += A[tid*130+i];
    dv[tid] = 1.0f / (sQZ + rsum);
  }
  __syncthreads();
  #pragma unroll
  for (int r=0;r<8;++r){
    int c = ty*8+r;
    float di = dv[c];
    float4 o; o.x=a2[r][0]*di; o.y=a2[r][1]*di; o.z=a2[r][2]*di; o.w=a2[r][3]*di;
    *(float4*)&outO[(size_t)(row0 + c)*64 + tx*4] = o;
  }
}

extern "C" void kernel_launch(void* const* d_in, const int* in_sizes, int n_in,
                              void* d_out, int out_size, void* d_ws, size_t ws_size,
                              hipStream_t stream){
  (void)in_sizes; (void)n_in; (void)out_size; (void)ws_size;
  const float* q    = (const float*)d_in[0];
  const float* k    = (const float*)d_in[1];
  const float* v    = (const float*)d_in[2];
  const float* proj = (const float*)d_in[3];

  char* ws = (char*)d_ws;
  unsigned* kmax = (unsigned*)ws;                                   // 256 B slot
  float*    projT= (float*)(ws + 256);                              // 65536 B
  ushort_t* qf   = (ushort_t*)(ws + 65792);                         // 33554432 B
  ushort_t* kf   = (ushort_t*)(ws + 65792 + 33554432);              // 33554432 B
  float*    Zl   = (float*)(ws + 65792 + 67108864);                 // 524288 B
  float*    Sl   = (float*)(ws + 65792 + 67108864 + 524288);        // 33554432 B

  float* outO = (float*)d_out;
  float* outZ = outO + (size_t)2*8*4096*64;   // 4194304
  float* outS = outZ + 2*8*256;               // +4096

  hipFuncSetAttribute((const void*)k_out, hipFuncAttributeMaxDynamicSharedMemorySize, 131072);

  k_prep <<<1,      256, 0, stream>>>(proj, projT, kmax);
  k_feat <<<1024,   256, 0, stream>>>(q, k, projT, qf, kf, kmax, 0);
  k_feat <<<512,    256, 0, stream>>>(q, k, projT, qf, kf, kmax, 1);
  k_chunk<<<512,    256, 0, stream>>>(kf, v, Zl, Sl);
  k_scan <<<16*65,  256, 0, stream>>>(Zl, Sl, outZ, outS);
  k_out  <<<512,    256, 128512, stream>>>(qf, kf, v, Zl, Sl, outO);
}

// Round 3
// 215.046 us; speedup vs baseline: 2.9427x; 1.7239x over previous
//
#include <hip/hip_runtime.h>

typedef unsigned short ushort_t;
typedef __attribute__((ext_vector_type(8))) short bf16x8;
typedef __attribute__((ext_vector_type(16))) float f32x16;

#define NORMC 0.35355339059327373f   // 64^-0.25
#define DIAGC 0.0625f                // 0.5 * 64^-0.5
#define RATIO 0.0625f                // 256^-0.5
#define KEPS  1e-4f
#define AEPS  1e-6f

__device__ __forceinline__ unsigned short f2bf(float f){
  unsigned u = __float_as_uint(f);
  unsigned r = (u + 0x7FFFu + ((u >> 16) & 1u)) >> 16;  // RNE
  return (unsigned short)r;
}
__device__ __forceinline__ float bf2f(unsigned short h){
  return __uint_as_float(((unsigned)h) << 16);
}
__device__ __forceinline__ unsigned enc_f(float f){
  unsigned u = __float_as_uint(f);
  return (u & 0x80000000u) ? ~u : (u | 0x80000000u);
}
__device__ __forceinline__ float dec_f(unsigned e){
  unsigned b = (e & 0x80000000u) ? (e ^ 0x80000000u) : ~e;
  return __uint_as_float(b);
}

// K0: projT[d][m] = NORMC * proj[m][d]; init global-max slot
__global__ void k_prep(const float* __restrict__ proj, float* __restrict__ projT,
                       unsigned* __restrict__ kmax){
  int t = threadIdx.x;
  if (t == 0) *kmax = 0u;
  for (int d = 0; d < 64; ++d) projT[d*256 + t] = NORMC * proj[t*64 + d];
}

// K1/K2: dash GEMM [128 rows x 256 m], K=64 in two 32-tiles.
__launch_bounds__(256)
__global__ void k_feat(const float* __restrict__ q, const float* __restrict__ k,
                       const float* __restrict__ projT,
                       ushort_t* __restrict__ qf, ushort_t* __restrict__ kf,
                       unsigned* __restrict__ kmax, int pass)
{
  __shared__ float pt[32*256];
  __shared__ float xt[128*33];
  __shared__ float wred[4];
  int tid = threadIdx.x;
  int mode, tile;
  if (pass == 0){
    if (blockIdx.x < 512){ mode = 0; tile = (int)blockIdx.x; }
    else                 { mode = 1; tile = (int)blockIdx.x - 512; }
  } else { mode = 2; tile = (int)blockIdx.x; }
  const float* src = (mode == 0) ? q : k;
  int row0 = tile * 128;
  int tx = tid & 15, ty = tid >> 4;

  float acc[8][16];
  #pragma unroll
  for (int r=0;r<8;++r){
    #pragma unroll
    for (int j=0;j<16;++j) acc[r][j]=0.f;
  }
  float dsum[8];
  #pragma unroll
  for (int r=0;r<8;++r) dsum[r]=0.f;

  for (int k0=0;k0<64;k0+=32){
    __syncthreads();
    for (int i=tid;i<32*256;i+=256) pt[i] = projT[k0*256 + i];
    for (int i=tid;i<128*32;i+=256){ int r=i>>5, d=i&31; xt[r*33+d] = src[(size_t)(row0+r)*64 + k0 + d]; }
    __syncthreads();
    #pragma unroll
    for (int r=0;r<8;++r){
      float x0 = xt[(ty*8+r)*33 + tx*2];
      float x1 = xt[(ty*8+r)*33 + tx*2 + 1];
      dsum[r] += x0*x0 + x1*x1;
    }
    for (int kk=0;kk<32;++kk){
      float a[8];
      #pragma unroll
      for (int r=0;r<8;++r) a[r] = xt[(ty*8+r)*33 + kk];
      const float4* pp = (const float4*)&pt[kk*256 + tx*16];
      #pragma unroll
      for (int jq=0;jq<4;++jq){
        float4 pv = pp[jq];
        #pragma unroll
        for (int r=0;r<8;++r){
          acc[r][jq*4+0] += a[r]*pv.x;
          acc[r][jq*4+1] += a[r]*pv.y;
          acc[r][jq*4+2] += a[r]*pv.z;
          acc[r][jq*4+3] += a[r]*pv.w;
        }
      }
    }
  }
  float rmax[8];
  #pragma unroll
  for (int r=0;r<8;++r){
    float mx = acc[r][0];
    #pragma unroll
    for (int j=1;j<16;++j) mx = fmaxf(mx, acc[r][j]);
    #pragma unroll
    for (int s=1;s<16;s<<=1) mx = fmaxf(mx, __shfl_xor(mx, s, 16));
    rmax[r] = mx;
    #pragma unroll
    for (int s=1;s<16;s<<=1) dsum[r] += __shfl_xor(dsum[r], s, 16);
  }

  if (mode == 1){
    float wm = rmax[0];
    #pragma unroll
    for (int r=1;r<8;++r) wm = fmaxf(wm, rmax[r]);
    wm = fmaxf(wm, __shfl_xor(wm, 16, 64));
    wm = fmaxf(wm, __shfl_xor(wm, 32, 64));
    if ((tid & 63) == 0) wred[tid>>6] = wm;
    __syncthreads();
    if (tid == 0){
      float m4 = fmaxf(fmaxf(wred[0],wred[1]), fmaxf(wred[2],wred[3]));
      atomicMax(kmax, enc_f(m4));
    }
    return;
  }
  float gm = 0.f;
  if (mode == 2) gm = dec_f(*kmax);
  ushort_t* dst = (mode==0) ? qf : kf;
  #pragma unroll
  for (int r=0;r<8;++r){
    float st = (mode==0) ? rmax[r] : gm;
    float dg = DIAGC * dsum[r];
    unsigned w[8];
    #pragma unroll
    for (int j2=0;j2<8;++j2){
      float v0 = RATIO * (__expf(acc[r][2*j2]   - dg - st) + KEPS);
      float v1 = RATIO * (__expf(acc[r][2*j2+1] - dg - st) + KEPS);
      w[j2] = (unsigned)f2bf(v0) | ((unsigned)f2bf(v1) << 16);
    }
    uint4* o = (uint4*)&dst[(size_t)(row0 + ty*8 + r)*256 + tx*16];
    o[0] = make_uint4(w[0],w[1],w[2],w[3]);
    o[1] = make_uint4(w[4],w[5],w[6],w[7]);
  }
}

// K3: per-chunk local sums. Zl[cb][m] = sum_c kf; Sl[cb][e][m] = sum_c kf[c,m]*v[c,e]
__launch_bounds__(256)
__global__ void k_chunk(const ushort_t* __restrict__ kf, const float* __restrict__ v,
                        float* __restrict__ Zl, float* __restrict__ Sl){
  __shared__ float vl[8][64];
  int tid = threadIdx.x;
  int bh = blockIdx.x >> 5, j = blockIdx.x & 31;
  int row0 = bh*4096 + j*128;
  float z = 0.f;
  float acc[64];
  #pragma unroll
  for (int e=0;e<64;++e) acc[e]=0.f;
  for (int c0=0;c0<128;c0+=8){
    __syncthreads();
    for (int i=tid;i<512;i+=256){ int c=i>>6, e=i&63; vl[c][e] = v[(size_t)(row0+c0+c)*64 + e]; }
    __syncthreads();
    for (int c=0;c<8;++c){
      float kv = bf2f(kf[(size_t)(row0+c0+c)*256 + tid]);
      z += kv;
      const float4* vp = (const float4*)vl[c];
      #pragma unroll
      for (int e4=0;e4<16;++e4){
        float4 vv = vp[e4];
        acc[e4*4+0]+=kv*vv.x; acc[e4*4+1]+=kv*vv.y; acc[e4*4+2]+=kv*vv.z; acc[e4*4+3]+=kv*vv.w;
      }
    }
  }
  int cb = bh*32 + j;
  Zl[(size_t)cb*256 + tid] = z;
  #pragma unroll
  for (int e=0;e<64;++e) Sl[(size_t)cb*16384 + (size_t)e*256 + tid] = acc[e];
}

// K4: parallel exclusive scan over the 32 chunks.
__launch_bounds__(256)
__global__ void k_scan(float* __restrict__ Zl, float* __restrict__ Sl,
                       float* __restrict__ outZ, float* __restrict__ outS){
  int t = threadIdx.x;
  int bh = blockIdx.x / 65;
  int s  = blockIdx.x % 65;
  if (s == 64){
    size_t base = (size_t)(bh*32)*256 + t;
    float rz = 0.f;
    #pragma unroll
    for (int j0=0;j0<32;j0+=8){
      float x[8];
      #pragma unroll
      for (int u=0;u<8;++u) x[u] = Zl[base + (size_t)(j0+u)*256];
      #pragma unroll
      for (int u=0;u<8;++u){ Zl[base + (size_t)(j0+u)*256] = rz; rz += x[u]; }
    }
    outZ[(size_t)bh*256 + t] = rz;
  } else {
    int e = s;
    size_t base = (size_t)(bh*32)*16384 + (size_t)e*256 + t;
    float rs = 0.f;
    #pragma unroll
    for (int j0=0;j0<32;j0+=8){
      float x[8];
      #pragma unroll
      for (int u=0;u<8;++u) x[u] = Sl[base + (size_t)(j0+u)*16384];
      #pragma unroll
      for (int u=0;u<8;++u){ Sl[base + (size_t)(j0+u)*16384] = rs; rs += x[u]; }
    }
    outS[(size_t)bh*16384 + (size_t)t*64 + e] = rs;
  }
}

// K_QZ: qz[row] = sum_m qf[row][m] * (Z0[chunk][m] + eps), fp32 exact.
// grid 512 (one block per chunk). Wave covers 8 rows x 128B coalesced reads.
__launch_bounds__(256)
__global__ void k_qz(const ushort_t* __restrict__ qf, const float* __restrict__ Zp,
                     float* __restrict__ qz){
  __shared__ float z0[256];
  int tid = threadIdx.x;
  int bh = blockIdx.x >> 5, j = blockIdx.x & 31;
  int row0 = bh*4096 + j*128;
  int pb = bh*32 + j;
  z0[tid] = Zp[(size_t)pb*256 + tid] + AEPS;
  __syncthreads();
  int l = tid & 63, w = tid >> 6;
  #pragma unroll
  for (int ri = 0; ri < 4; ++ri){
    int row = ri*32 + w*8 + (l>>3);
    float s = 0.f;
    #pragma unroll
    for (int seg=0; seg<4; ++seg){
      int m = seg*64 + (l&7)*8;
      uint4 u = *(const uint4*)(qf + (size_t)(row0+row)*256 + m);
      float4 za = *(const float4*)&z0[m];
      float4 zb = *(const float4*)&z0[m+4];
      s += bf2f((ushort_t)(u.x&0xffffu))*za.x + bf2f((ushort_t)(u.x>>16))*za.y
         + bf2f((ushort_t)(u.y&0xffffu))*za.z + bf2f((ushort_t)(u.y>>16))*za.w
         + bf2f((ushort_t)(u.z&0xffffu))*zb.x + bf2f((ushort_t)(u.z>>16))*zb.y
         + bf2f((ushort_t)(u.w&0xffffu))*zb.z + bf2f((ushort_t)(u.w>>16))*zb.w;
    }
    s += __shfl_xor(s,1); s += __shfl_xor(s,2); s += __shfl_xor(s,4);
    if ((l&7)==0) qz[(size_t)row0 + row] = s;
  }
}

// K5 (MFMA): per-chunk output.
// Phase A: A = tril(qf * kf^T) -> bf16 in LDS (swizzled); exact fp32 rowsums via shuffle.
// Phase B: numer[128][64] = A*v + qf*S0 over 6 K=64 tiles; out = numer / (rowsum + qz).
__launch_bounds__(256)
__global__ void k_out(const ushort_t* __restrict__ qf, const ushort_t* __restrict__ kf,
                      const float* __restrict__ v, const float* __restrict__ Sp,
                      const float* __restrict__ qz, float* __restrict__ outO){
  extern __shared__ char smc[];
  char* Ab  = smc;                 // A_lds bf16 [128][128], rows 256B, chunk swizzle ^(r&15)
  char* qtb = smc + 32768;         // qt bf16 [128][64], rows 128B, swizzle ^(r&7)
  char* ktb = smc + 49152;         // kt (phase A) -- aliased below after phase A
  char* bTb = smc + 49152;         // bT bf16 [64][64], rows 128B, swizzle ^(e&7)
  float* rsum = (float*)(smc + 49152 + 8192);  // [128] f32

  int tid = threadIdx.x;
  int w   = tid >> 6;
  int lane= tid & 63;
  int l31 = lane & 31;
  int half= lane >> 5;
  int arow= 32*w + l31;            // this wave's A-operand row (q row)
  int bh = blockIdx.x >> 5, j = blockIdx.x & 31;
  int row0 = bh*4096 + j*128;
  size_t qbase = (size_t)row0*256;
  int pb = bh*32 + j;

  // ---------------- Phase A: A = qf * kf^T (lower triangle only) ----------------
  f32x16 acc[4];
  #pragma unroll
  for (int ct=0;ct<4;++ct){
    #pragma unroll
    for (int r=0;r<16;++r) acc[ct][r] = 0.f;
  }

  for (int m0=0;m0<256;m0+=64){
    __syncthreads();
    #pragma unroll
    for (int u=0;u<4;++u){
      int ci = tid*4+u; int rr = ci>>3, c8 = ci&7;
      int sw = (c8*16) ^ ((rr&7)<<4);
      *(uint4*)(qtb + rr*128 + sw) = *(const uint4*)(qf + qbase + (size_t)rr*256 + m0 + c8*8);
      *(uint4*)(ktb + rr*128 + sw) = *(const uint4*)(kf + qbase + (size_t)rr*256 + m0 + c8*8);
    }
    __syncthreads();
    #pragma unroll
    for (int ks=0;ks<4;++ks){
      bf16x8 af = *(const bf16x8*)(qtb + arow*128 + ((ks*32 + half*16) ^ ((arow&7)<<4)));
      #pragma unroll
      for (int ct=0;ct<4;++ct){
        if (ct <= w){
          int br = ct*32 + l31;
          bf16x8 bf = *(const bf16x8*)(ktb + br*128 + ((ks*32 + half*16) ^ ((br&7)<<4)));
          acc[ct] = __builtin_amdgcn_mfma_f32_32x32x16_bf16(af, bf, acc[ct], 0, 0, 0);
        }
      }
    }
  }

  // mask, write A_lds (bf16), exact fp32 rowsums
  float p[16];
  #pragma unroll
  for (int r=0;r<16;++r) p[r]=0.f;
  #pragma unroll
  for (int ct=0;ct<4;++ct){
    #pragma unroll
    for (int r=0;r<16;++r){
      int grow = 32*w + (r&3) + 8*(r>>2) + 4*half;
      int col  = ct*32 + l31;
      float m = (col <= grow) ? acc[ct][r] : 0.f;
      p[r] += m;
      *(ushort_t*)(Ab + grow*256 + ((col*2) ^ ((grow&15)<<4))) = f2bf(m);
    }
  }
  #pragma unroll
  for (int s=1;s<32;s<<=1){
    #pragma unroll
    for (int r=0;r<16;++r) p[r] += __shfl_xor(p[r], s);
  }
  __syncthreads();             // kt reads done; safe to alias bT/rsum over ktb
  if (l31 == 0){
    #pragma unroll
    for (int r=0;r<16;++r) rsum[32*w + (r&3) + 8*(r>>2) + 4*half] = p[r];
  }

  // ---------------- Phase B: numer = A*v + qf*S0 ----------------
  f32x16 acc2[2];
  #pragma unroll
  for (int ct=0;ct<2;++ct){
    #pragma unroll
    for (int r=0;r<16;++r) acc2[ct][r] = 0.f;
  }

  for (int kt_i=0; kt_i<6; ++kt_i){
    __syncthreads();
    if (kt_i < 2){
      // bT[e][i] = bf16(v[row0 + kt_i*64 + i][e])  (transpose)
      #pragma unroll
      for (int u=0;u<4;++u){
        int idx = tid*4+u; int rr = idx>>4, c4 = idx&15;
        float4 vv = *(const float4*)&v[(size_t)(row0 + kt_i*64 + rr)*64 + c4*4];
        #pragma unroll
        for (int jj=0;jj<4;++jj){
          int e = c4*4 + jj;
          float val = (jj==0)?vv.x:(jj==1)?vv.y:(jj==2)?vv.z:vv.w;
          *(ushort_t*)(bTb + e*128 + ((rr*2) ^ ((e&7)<<4))) = f2bf(val);
        }
      }
    } else {
      int m0 = (kt_i-2)*64;
      // bT[e][kl] = bf16(S0[m0+kl][e]) ; Sp layout [pb][e][m]
      #pragma unroll
      for (int u=0;u<4;++u){
        int idx = tid*4+u; int e = idx>>4, c4 = idx&15;
        float4 sv = *(const float4*)&Sp[(size_t)pb*16384 + (size_t)e*256 + m0 + c4*4];
        #pragma unroll
        for (int jj=0;jj<4;++jj){
          int kl = c4*4 + jj;
          float val = (jj==0)?sv.x:(jj==1)?sv.y:(jj==2)?sv.z:sv.w;
          *(ushort_t*)(bTb + e*128 + ((kl*2) ^ ((e&7)<<4))) = f2bf(val);
        }
      }
      // reload qt for this m-tile
      #pragma unroll
      for (int u=0;u<4;++u){
        int ci = tid*4+u; int rr = ci>>3, c8 = ci&7;
        *(uint4*)(qtb + rr*128 + ((c8*16) ^ ((rr&7)<<4))) =
            *(const uint4*)(qf + qbase + (size_t)rr*256 + m0 + c8*8);
      }
    }
    __syncthreads();
    #pragma unroll
    for (int ks=0;ks<4;++ks){
      bf16x8 af;
      bool doit = true;
      if (kt_i < 2){
        doit = (kt_i*64 + ks*16 <= 32*w + 31);   // wave-uniform: A zero above diagonal
        if (doit)
          af = *(const bf16x8*)(Ab + arow*256 + ((kt_i*128 + ks*32 + half*16) ^ ((arow&15)<<4)));
      } else {
        af = *(const bf16x8*)(qtb + arow*128 + ((ks*32 + half*16) ^ ((arow&7)<<4)));
      }
      if (doit){
        #pragma unroll
        for (int ct2=0;ct2<2;++ct2){
          int br = ct2*32 + l31;
          bf16x8 bf = *(const bf16x8*)(bTb + br*128 + ((ks*32 + half*16) ^ ((br&7)<<4)));
          acc2[ct2] = __builtin_amdgcn_mfma_f32_32x32x16_bf16(af, bf, acc2[ct2], 0, 0, 0);
        }
      }
    }
  }

  // ---------------- epilogue: divide & store ----------------
  __syncthreads();
  if (tid < 128) rsum[tid] = 1.0f / (rsum[tid] + qz[(size_t)row0 + tid]);
  __syncthreads();
  float dvv[16];
  #pragma unroll
  for (int r=0;r<16;++r) dvv[r] = rsum[32*w + (r&3) + 8*(r>>2) + 4*half];
  #pragma unroll
  for (int ct2=0;ct2<2;++ct2){
    #pragma unroll
    for (int r=0;r<16;++r){
      int qrow = 32*w + (r&3) + 8*(r>>2) + 4*half;
      int e = ct2*32 + l31;
      outO[(size_t)(row0+qrow)*64 + e] = acc2[ct2][r] * dvv[r];
    }
  }
}

extern "C" void kernel_launch(void* const* d_in, const int* in_sizes, int n_in,
                              void* d_out, int out_size, void* d_ws, size_t ws_size,
                              hipStream_t stream){
  (void)in_sizes; (void)n_in; (void)out_size; (void)ws_size;
  const float* q    = (const float*)d_in[0];
  const float* k    = (const float*)d_in[1];
  const float* v    = (const float*)d_in[2];
  const float* proj = (const float*)d_in[3];

  char* ws = (char*)d_ws;
  unsigned* kmax = (unsigned*)ws;                                   // 256 B slot
  float*    projT= (float*)(ws + 256);                              // 65536 B
  ushort_t* qf   = (ushort_t*)(ws + 65792);                         // 33554432 B
  ushort_t* kf   = (ushort_t*)(ws + 65792 + 33554432);              // 33554432 B
  float*    Zl   = (float*)(ws + 65792 + 67108864);                 // 524288 B
  float*    Sl   = (float*)(ws + 65792 + 67108864 + 524288);        // 33554432 B
  float*    qzb  = (float*)(ws + 65792 + 67108864 + 524288 + 33554432); // 262144 B

  float* outO = (float*)d_out;
  float* outZ = outO + (size_t)2*8*4096*64;
  float* outS = outZ + 2*8*256;

  hipFuncSetAttribute((const void*)k_out, hipFuncAttributeMaxDynamicSharedMemorySize, 65536);

  k_prep <<<1,      256, 0, stream>>>(proj, projT, kmax);
  k_feat <<<1024,   256, 0, stream>>>(q, k, projT, qf, kf, kmax, 0);
  k_feat <<<512,    256, 0, stream>>>(q, k, projT, qf, kf, kmax, 1);
  k_chunk<<<512,    256, 0, stream>>>(kf, v, Zl, Sl);
  k_scan <<<16*65,  256, 0, stream>>>(Zl, Sl, outZ, outS);
  k_qz   <<<512,    256, 0, stream>>>(qf, Zl, qzb);
  k_out  <<<512,    256, 65536, stream>>>(qf, kf, v, Sl, qzb, outO);
}

// Round 4
// 178.957 us; speedup vs baseline: 3.5362x; 1.2017x over previous
//
#include <hip/hip_runtime.h>

typedef unsigned short ushort_t;
typedef __attribute__((ext_vector_type(8))) short bf16x8;
typedef __attribute__((ext_vector_type(16))) float f32x16;

#define NORMC 0.35355339059327373f   // 64^-0.25
#define DIAGC 0.0625f                // 0.5 * 64^-0.5
#define RATIO 0.0625f                // 256^-0.5
#define KEPS  1e-4f
#define AEPS  1e-6f

__device__ __forceinline__ unsigned short f2bf(float f){
  unsigned u = __float_as_uint(f);
  unsigned r = (u + 0x7FFFu + ((u >> 16) & 1u)) >> 16;  // RNE
  return (unsigned short)r;
}
__device__ __forceinline__ float bf2f(unsigned short h){
  return __uint_as_float(((unsigned)h) << 16);
}
__device__ __forceinline__ unsigned enc_f(float f){
  unsigned u = __float_as_uint(f);
  return (u & 0x80000000u) ? ~u : (u | 0x80000000u);
}
__device__ __forceinline__ float dec_f(unsigned e){
  unsigned b = (e & 0x80000000u) ? (e ^ 0x80000000u) : ~e;
  return __uint_as_float(b);
}

// K0: split NORMC*proj into bf16 hi/lo, stored [m][d] (B-operand layout); init global-max slot
__global__ void k_prep(const float* __restrict__ proj, ushort_t* __restrict__ pjh,
                       ushort_t* __restrict__ pjl, unsigned* __restrict__ kmax){
  int t = threadIdx.x;   // m = t
  if (t == 0) *kmax = 0u;
  for (int d = 0; d < 64; ++d){
    float val = NORMC * proj[t*64 + d];
    unsigned short hi = f2bf(val);
    float lo = val - bf2f(hi);
    pjh[t*64 + d] = hi;
    pjl[t*64 + d] = f2bf(lo);
  }
}

// K1/K2 (MFMA): dash = x@P via hi/lo split (fp32-accurate).
// Block: 128 rows x 256 cols, 4 waves (32 rows each), K=64 in regs.
// pass=0: blocks 0..511 = q (rowmax stab, store qf); 512..1023 = k (global max only)
// pass=1: k rows, store kf using global max
__launch_bounds__(256)
__global__ void k_feat(const float* __restrict__ q, const float* __restrict__ k,
                       const ushort_t* __restrict__ pjh, const ushort_t* __restrict__ pjl,
                       ushort_t* __restrict__ qf, ushort_t* __restrict__ kf,
                       unsigned* __restrict__ kmax, int pass)
{
  extern __shared__ char sm[];
  char* ph = sm;            // [256 cols][128B] bf16 proj-hi, swizzle ^((col&7)<<4)
  char* pl = sm + 32768;    // proj-lo, same layout
  __shared__ float wred[4];

  int tid = threadIdx.x;
  int w   = tid >> 6;
  int lane= tid & 63;
  int l31 = lane & 31;
  int half= lane >> 5;

  int mode, tile;
  if (pass == 0){
    if (blockIdx.x < 512){ mode = 0; tile = (int)blockIdx.x; }
    else                 { mode = 1; tile = (int)blockIdx.x - 512; }
  } else { mode = 2; tile = (int)blockIdx.x; }
  const float* src = (mode == 0) ? q : k;
  int row0 = tile * 128;
  int row  = row0 + 32*w + l31;

  // stage proj hi/lo into LDS (once; coalesced uint4, swizzled rows)
  for (int i = tid; i < 2048; i += 256){
    int rr = i >> 3, c8 = i & 7;
    int off = rr*128 + ((c8*16) ^ ((rr&7)<<4));
    *(uint4*)(ph + off) = *(const uint4*)(pjh + rr*64 + c8*8);
    *(uint4*)(pl + off) = *(const uint4*)(pjl + rr*64 + c8*8);
  }

  // load this lane's A-fragment row slice, split hi/lo in regs; accumulate sum(x^2)
  bf16x8 ah[4], al[4];
  float dsum = 0.f;
  const float* rp = src + (size_t)row*64;
  #pragma unroll
  for (int ks=0; ks<4; ++ks){
    float4 x0 = *(const float4*)(rp + ks*16 + half*8);
    float4 x1 = *(const float4*)(rp + ks*16 + half*8 + 4);
    float xs[8] = {x0.x,x0.y,x0.z,x0.w,x1.x,x1.y,x1.z,x1.w};
    #pragma unroll
    for (int u=0; u<8; ++u){
      float xv = xs[u];
      dsum += xv*xv;
      unsigned short hi = f2bf(xv);
      float lo = xv - bf2f(hi);
      ah[ks][u] = (short)hi;
      al[ks][u] = (short)f2bf(lo);
    }
  }
  dsum += __shfl_xor(dsum, 32);   // full row sum over 64 dims

  f32x16 acc[8];
  #pragma unroll
  for (int ct=0; ct<8; ++ct){
    #pragma unroll
    for (int r=0; r<16; ++r) acc[ct][r] = 0.f;
  }
  __syncthreads();

  #pragma unroll
  for (int ct=0; ct<8; ++ct){
    int col = ct*32 + l31;
    #pragma unroll
    for (int ks=0; ks<4; ++ks){
      int boff = col*128 + ((ks*32 + half*16) ^ ((col&7)<<4));
      bf16x8 bh = *(const bf16x8*)(ph + boff);
      bf16x8 bl = *(const bf16x8*)(pl + boff);
      acc[ct] = __builtin_amdgcn_mfma_f32_32x32x16_bf16(ah[ks], bh, acc[ct], 0, 0, 0);
      acc[ct] = __builtin_amdgcn_mfma_f32_32x32x16_bf16(al[ks], bh, acc[ct], 0, 0, 0);
      acc[ct] = __builtin_amdgcn_mfma_f32_32x32x16_bf16(ah[ks], bl, acc[ct], 0, 0, 0);
    }
  }

  // per-row max over 256 cols (C layout: col=l31, row=(r&3)+8*(r>>2)+4*half)
  float rmax[16];
  #pragma unroll
  for (int r=0; r<16; ++r){
    float mx = acc[0][r];
    #pragma unroll
    for (int ct=1; ct<8; ++ct) mx = fmaxf(mx, acc[ct][r]);
    #pragma unroll
    for (int s=1; s<32; s<<=1) mx = fmaxf(mx, __shfl_xor(mx, s));
    rmax[r] = mx;
  }

  if (mode == 1){
    float wm = rmax[0];
    #pragma unroll
    for (int r=1; r<16; ++r) wm = fmaxf(wm, rmax[r]);
    wm = fmaxf(wm, __shfl_xor(wm, 32));
    if (lane == 0) wred[w] = wm;
    __syncthreads();
    if (tid == 0){
      float m4 = fmaxf(fmaxf(wred[0],wred[1]), fmaxf(wred[2],wred[3]));
      atomicMax(kmax, enc_f(m4));
    }
    return;
  }
  float gm = 0.f;
  if (mode == 2) gm = dec_f(*kmax);

  // diag per C-layout row (shuffle dsum from the lane holding that row)
  float diagv[16];
  #pragma unroll
  for (int r=0; r<16; ++r){
    int lrow = (r&3) + 8*(r>>2) + 4*half;
    diagv[r] = DIAGC * __shfl(dsum, lrow);
  }

  // compute features, stage into LDS (reusing proj region), coalesced store
  __syncthreads();   // all MFMA LDS reads done; safe to overwrite ph/pl
  char* ob = sm;     // [128 rows][512B] ushort
  #pragma unroll
  for (int r=0; r<16; ++r){
    int lrow = 32*w + (r&3) + 8*(r>>2) + 4*half;
    float st = (mode==0) ? rmax[r] : gm;
    float dg = diagv[r];
    #pragma unroll
    for (int ct=0; ct<8; ++ct){
      float val = RATIO * (__expf(acc[ct][r] - dg - st) + KEPS);
      *(ushort_t*)(ob + lrow*512 + (ct*32 + l31)*2) = f2bf(val);
    }
  }
  __syncthreads();
  ushort_t* dst = ((mode==0) ? qf : kf) + (size_t)row0*256;
  for (int i = tid; i < 4096; i += 256)
    *(uint4*)(dst + i*8) = *(const uint4*)(ob + i*16);
}

// K3: per-chunk local sums. Zl[cb][m] = sum_c kf; Sl[cb][e][m] = sum_c kf[c,m]*v[c,e]
__launch_bounds__(256)
__global__ void k_chunk(const ushort_t* __restrict__ kf, const float* __restrict__ v,
                        float* __restrict__ Zl, float* __restrict__ Sl){
  __shared__ float vl[8][64];
  int tid = threadIdx.x;
  int bh = blockIdx.x >> 5, j = blockIdx.x & 31;
  int row0 = bh*4096 + j*128;
  float z = 0.f;
  float acc[64];
  #pragma unroll
  for (int e=0;e<64;++e) acc[e]=0.f;
  for (int c0=0;c0<128;c0+=8){
    __syncthreads();
    for (int i=tid;i<512;i+=256){ int c=i>>6, e=i&63; vl[c][e] = v[(size_t)(row0+c0+c)*64 + e]; }
    __syncthreads();
    for (int c=0;c<8;++c){
      float kv = bf2f(kf[(size_t)(row0+c0+c)*256 + tid]);
      z += kv;
      const float4* vp = (const float4*)vl[c];
      #pragma unroll
      for (int e4=0;e4<16;++e4){
        float4 vv = vp[e4];
        acc[e4*4+0]+=kv*vv.x; acc[e4*4+1]+=kv*vv.y; acc[e4*4+2]+=kv*vv.z; acc[e4*4+3]+=kv*vv.w;
      }
    }
  }
  int cb = bh*32 + j;
  Zl[(size_t)cb*256 + tid] = z;
  #pragma unroll
  for (int e=0;e<64;++e) Sl[(size_t)cb*16384 + (size_t)e*256 + tid] = acc[e];
}

// K4: parallel exclusive scan over the 32 chunks.
__launch_bounds__(256)
__global__ void k_scan(float* __restrict__ Zl, float* __restrict__ Sl,
                       float* __restrict__ outZ, float* __restrict__ outS){
  int t = threadIdx.x;
  int bh = blockIdx.x / 65;
  int s  = blockIdx.x % 65;
  if (s == 64){
    size_t base = (size_t)(bh*32)*256 + t;
    float rz = 0.f;
    #pragma unroll
    for (int j0=0;j0<32;j0+=8){
      float x[8];
      #pragma unroll
      for (int u=0;u<8;++u) x[u] = Zl[base + (size_t)(j0+u)*256];
      #pragma unroll
      for (int u=0;u<8;++u){ Zl[base + (size_t)(j0+u)*256] = rz; rz += x[u]; }
    }
    outZ[(size_t)bh*256 + t] = rz;
  } else {
    int e = s;
    size_t base = (size_t)(bh*32)*16384 + (size_t)e*256 + t;
    float rs = 0.f;
    #pragma unroll
    for (int j0=0;j0<32;j0+=8){
      float x[8];
      #pragma unroll
      for (int u=0;u<8;++u) x[u] = Sl[base + (size_t)(j0+u)*16384];
      #pragma unroll
      for (int u=0;u<8;++u){ Sl[base + (size_t)(j0+u)*16384] = rs; rs += x[u]; }
    }
    outS[(size_t)bh*16384 + (size_t)t*64 + e] = rs;
  }
}

// K_QZ: qz[row] = sum_m qf[row][m] * (Z0[chunk][m] + eps), fp32 exact.
__launch_bounds__(256)
__global__ void k_qz(const ushort_t* __restrict__ qf, const float* __restrict__ Zp,
                     float* __restrict__ qz){
  __shared__ float z0[256];
  int tid = threadIdx.x;
  int bh = blockIdx.x >> 5, j = blockIdx.x & 31;
  int row0 = bh*4096 + j*128;
  int pb = bh*32 + j;
  z0[tid] = Zp[(size_t)pb*256 + tid] + AEPS;
  __syncthreads();
  int l = tid & 63, w = tid >> 6;
  #pragma unroll
  for (int ri = 0; ri < 4; ++ri){
    int row = ri*32 + w*8 + (l>>3);
    float s = 0.f;
    #pragma unroll
    for (int seg=0; seg<4; ++seg){
      int m = seg*64 + (l&7)*8;
      uint4 u = *(const uint4*)(qf + (size_t)(row0+row)*256 + m);
      float4 za = *(const float4*)&z0[m];
      float4 zb = *(const float4*)&z0[m+4];
      s += bf2f((ushort_t)(u.x&0xffffu))*za.x + bf2f((ushort_t)(u.x>>16))*za.y
         + bf2f((ushort_t)(u.y&0xffffu))*za.z + bf2f((ushort_t)(u.y>>16))*za.w
         + bf2f((ushort_t)(u.z&0xffffu))*zb.x + bf2f((ushort_t)(u.z>>16))*zb.y
         + bf2f((ushort_t)(u.w&0xffffu))*zb.z + bf2f((ushort_t)(u.w>>16))*zb.w;
    }
    s += __shfl_xor(s,1); s += __shfl_xor(s,2); s += __shfl_xor(s,4);
    if ((l&7)==0) qz[(size_t)row0 + row] = s;
  }
}

// K5 (MFMA): per-chunk output.
__launch_bounds__(256)
__global__ void k_out(const ushort_t* __restrict__ qf, const ushort_t* __restrict__ kf,
                      const float* __restrict__ v, const float* __restrict__ Sp,
                      const float* __restrict__ qz, float* __restrict__ outO){
  extern __shared__ char smc[];
  char* Ab  = smc;                 // A_lds bf16 [128][128], rows 256B, swizzle ^((r&15)<<4)
  char* qtb = smc + 32768;         // qt bf16 [128][64], rows 128B, swizzle ^((r&7)<<4)
  char* ktb = smc + 49152;         // kt (phase A) -- aliased by bT after phase A
  char* bTb = smc + 49152;         // bT bf16 [64][64], rows 128B, swizzle ^((e&7)<<4)
  float* rsum = (float*)(smc + 49152 + 8192);  // [128] f32

  int tid = threadIdx.x;
  int w   = tid >> 6;
  int lane= tid & 63;
  int l31 = lane & 31;
  int half= lane >> 5;
  int arow= 32*w + l31;
  int bh = blockIdx.x >> 5, j = blockIdx.x & 31;
  int row0 = bh*4096 + j*128;
  size_t qbase = (size_t)row0*256;
  int pb = bh*32 + j;

  // ---------------- Phase A: A = qf * kf^T (lower triangle only) ----------------
  f32x16 acc[4];
  #pragma unroll
  for (int ct=0;ct<4;++ct){
    #pragma unroll
    for (int r=0;r<16;++r) acc[ct][r] = 0.f;
  }

  for (int m0=0;m0<256;m0+=64){
    __syncthreads();
    #pragma unroll
    for (int u=0;u<4;++u){
      int ci = tid*4+u; int rr = ci>>3, c8 = ci&7;
      int sw = (c8*16) ^ ((rr&7)<<4);
      *(uint4*)(qtb + rr*128 + sw) = *(const uint4*)(qf + qbase + (size_t)rr*256 + m0 + c8*8);
      *(uint4*)(ktb + rr*128 + sw) = *(const uint4*)(kf + qbase + (size_t)rr*256 + m0 + c8*8);
    }
    __syncthreads();
    #pragma unroll
    for (int ks=0;ks<4;++ks){
      bf16x8 af = *(const bf16x8*)(qtb + arow*128 + ((ks*32 + half*16) ^ ((arow&7)<<4)));
      #pragma unroll
      for (int ct=0;ct<4;++ct){
        if (ct <= w){
          int br = ct*32 + l31;
          bf16x8 bf = *(const bf16x8*)(ktb + br*128 + ((ks*32 + half*16) ^ ((br&7)<<4)));
          acc[ct] = __builtin_amdgcn_mfma_f32_32x32x16_bf16(af, bf, acc[ct], 0, 0, 0);
        }
      }
    }
  }

  float p[16];
  #pragma unroll
  for (int r=0;r<16;++r) p[r]=0.f;
  #pragma unroll
  for (int ct=0;ct<4;++ct){
    #pragma unroll
    for (int r=0;r<16;++r){
      int grow = 32*w + (r&3) + 8*(r>>2) + 4*half;
      int col  = ct*32 + l31;
      float m = (col <= grow) ? acc[ct][r] : 0.f;
      p[r] += m;
      *(ushort_t*)(Ab + grow*256 + ((col*2) ^ ((grow&15)<<4))) = f2bf(m);
    }
  }
  #pragma unroll
  for (int s=1;s<32;s<<=1){
    #pragma unroll
    for (int r=0;r<16;++r) p[r] += __shfl_xor(p[r], s);
  }
  __syncthreads();
  if (l31 == 0){
    #pragma unroll
    for (int r=0;r<16;++r) rsum[32*w + (r&3) + 8*(r>>2) + 4*half] = p[r];
  }

  // ---------------- Phase B: numer = A*v + qf*S0 ----------------
  f32x16 acc2[2];
  #pragma unroll
  for (int ct=0;ct<2;++ct){
    #pragma unroll
    for (int r=0;r<16;++r) acc2[ct][r] = 0.f;
  }

  for (int kt_i=0; kt_i<6; ++kt_i){
    __syncthreads();
    if (kt_i < 2){
      #pragma unroll
      for (int u=0;u<4;++u){
        int idx = tid*4+u; int rr = idx>>4, c4 = idx&15;
        float4 vv = *(const float4*)&v[(size_t)(row0 + kt_i*64 + rr)*64 + c4*4];
        #pragma unroll
        for (int jj=0;jj<4;++jj){
          int e = c4*4 + jj;
          float val = (jj==0)?vv.x:(jj==1)?vv.y:(jj==2)?vv.z:vv.w;
          *(ushort_t*)(bTb + e*128 + ((rr*2) ^ ((e&7)<<4))) = f2bf(val);
        }
      }
    } else {
      int m0 = (kt_i-2)*64;
      #pragma unroll
      for (int u=0;u<4;++u){
        int idx = tid*4+u; int e = idx>>4, c4 = idx&15;
        float4 sv = *(const float4*)&Sp[(size_t)pb*16384 + (size_t)e*256 + m0 + c4*4];
        #pragma unroll
        for (int jj=0;jj<4;++jj){
          int kl = c4*4 + jj;
          float val = (jj==0)?sv.x:(jj==1)?sv.y:(jj==2)?sv.z:sv.w;
          *(ushort_t*)(bTb + e*128 + ((kl*2) ^ ((e&7)<<4))) = f2bf(val);
        }
      }
      #pragma unroll
      for (int u=0;u<4;++u){
        int ci = tid*4+u; int rr = ci>>3, c8 = ci&7;
        *(uint4*)(qtb + rr*128 + ((c8*16) ^ ((rr&7)<<4))) =
            *(const uint4*)(qf + qbase + (size_t)rr*256 + m0 + c8*8);
      }
    }
    __syncthreads();
    #pragma unroll
    for (int ks=0;ks<4;++ks){
      bf16x8 af;
      bool doit = true;
      if (kt_i < 2){
        doit = (kt_i*64 + ks*16 <= 32*w + 31);
        if (doit)
          af = *(const bf16x8*)(Ab + arow*256 + ((kt_i*128 + ks*32 + half*16) ^ ((arow&15)<<4)));
      } else {
        af = *(const bf16x8*)(qtb + arow*128 + ((ks*32 + half*16) ^ ((arow&7)<<4)));
      }
      if (doit){
        #pragma unroll
        for (int ct2=0;ct2<2;++ct2){
          int br = ct2*32 + l31;
          bf16x8 bf = *(const bf16x8*)(bTb + br*128 + ((ks*32 + half*16) ^ ((br&7)<<4)));
          acc2[ct2] = __builtin_amdgcn_mfma_f32_32x32x16_bf16(af, bf, acc2[ct2], 0, 0, 0);
        }
      }
    }
  }

  __syncthreads();
  if (tid < 128) rsum[tid] = 1.0f / (rsum[tid] + qz[(size_t)row0 + tid]);
  __syncthreads();
  float dvv[16];
  #pragma unroll
  for (int r=0;r<16;++r) dvv[r] = rsum[32*w + (r&3) + 8*(r>>2) + 4*half];
  #pragma unroll
  for (int ct2=0;ct2<2;++ct2){
    #pragma unroll
    for (int r=0;r<16;++r){
      int qrow = 32*w + (r&3) + 8*(r>>2) + 4*half;
      int e = ct2*32 + l31;
      outO[(size_t)(row0+qrow)*64 + e] = acc2[ct2][r] * dvv[r];
    }
  }
}

extern "C" void kernel_launch(void* const* d_in, const int* in_sizes, int n_in,
                              void* d_out, int out_size, void* d_ws, size_t ws_size,
                              hipStream_t stream){
  (void)in_sizes; (void)n_in; (void)out_size; (void)ws_size;
  const float* q    = (const float*)d_in[0];
  const float* k    = (const float*)d_in[1];
  const float* v    = (const float*)d_in[2];
  const float* proj = (const float*)d_in[3];

  char* ws = (char*)d_ws;
  unsigned* kmax = (unsigned*)ws;                                   // 256 B slot
  ushort_t* pjh  = (ushort_t*)(ws + 256);                           // 32768 B
  ushort_t* pjl  = (ushort_t*)(ws + 256 + 32768);                   // 32768 B
  ushort_t* qf   = (ushort_t*)(ws + 65792);                         // 33554432 B
  ushort_t* kf   = (ushort_t*)(ws + 65792 + 33554432);              // 33554432 B
  float*    Zl   = (float*)(ws + 65792 + 67108864);                 // 524288 B
  float*    Sl   = (float*)(ws + 65792 + 67108864 + 524288);        // 33554432 B
  float*    qzb  = (float*)(ws + 65792 + 67108864 + 524288 + 33554432); // 262144 B

  float* outO = (float*)d_out;
  float* outZ = outO + (size_t)2*8*4096*64;
  float* outS = outZ + 2*8*256;

  hipFuncSetAttribute((const void*)k_feat, hipFuncAttributeMaxDynamicSharedMemorySize, 65536);
  hipFuncSetAttribute((const void*)k_out,  hipFuncAttributeMaxDynamicSharedMemorySize, 65536);

  k_prep <<<1,      256, 0, stream>>>(proj, pjh, pjl, kmax);
  k_feat <<<1024,   256, 65536, stream>>>(q, k, pjh, pjl, qf, kf, kmax, 0);
  k_feat <<<512,    256, 65536, stream>>>(q, k, pjh, pjl, qf, kf, kmax, 1);
  k_chunk<<<512,    256, 0, stream>>>(kf, v, Zl, Sl);
  k_scan <<<16*65,  256, 0, stream>>>(Zl, Sl, outZ, outS);
  k_qz   <<<512,    256, 0, stream>>>(qf, Zl, qzb);
  k_out  <<<512,    256, 65536, stream>>>(qf, kf, v, Sl, qzb, outO);
}

// Round 5
// 139.271 us; speedup vs baseline: 4.5438x; 1.2850x over previous
//
#include <hip/hip_runtime.h>

typedef unsigned short ushort_t;
typedef __attribute__((ext_vector_type(8))) short bf16x8;
typedef __attribute__((ext_vector_type(16))) float f32x16;

#define NORMC 0.35355339059327373f   // 64^-0.25
#define DIAGC 0.0625f                // 0.5 * 64^-0.5
#define RATIO 0.0625f                // 256^-0.5
#define KEPS  1e-4f
#define AEPS  1e-6f

__device__ __forceinline__ unsigned short f2bf(float f){
  unsigned u = __float_as_uint(f);
  unsigned r = (u + 0x7FFFu + ((u >> 16) & 1u)) >> 16;  // RNE
  return (unsigned short)r;
}
__device__ __forceinline__ float bf2f(unsigned short h){
  return __uint_as_float(((unsigned)h) << 16);
}
__device__ __forceinline__ unsigned enc_f(float f){
  unsigned u = __float_as_uint(f);
  return (u & 0x80000000u) ? ~u : (u | 0x80000000u);
}
__device__ __forceinline__ float dec_f(unsigned e){
  unsigned b = (e & 0x80000000u) ? (e ^ 0x80000000u) : ~e;
  return __uint_as_float(b);
}

// K0: split NORMC*proj into bf16 hi/lo, stored [m][d] (B-operand layout); init global-max slot
__global__ void k_prep(const float* __restrict__ proj, ushort_t* __restrict__ pjh,
                       ushort_t* __restrict__ pjl, unsigned* __restrict__ kmax){
  int t = threadIdx.x;   // m = t
  if (t == 0) *kmax = 0u;
  for (int d = 0; d < 64; ++d){
    float val = NORMC * proj[t*64 + d];
    unsigned short hi = f2bf(val);
    float lo = val - bf2f(hi);
    pjh[t*64 + d] = hi;
    pjl[t*64 + d] = f2bf(lo);
  }
}

// K1/K2 (MFMA): dash = x@P via hi/lo split (fp32-accurate).
__launch_bounds__(256)
__global__ void k_feat(const float* __restrict__ q, const float* __restrict__ k,
                       const ushort_t* __restrict__ pjh, const ushort_t* __restrict__ pjl,
                       ushort_t* __restrict__ qf, ushort_t* __restrict__ kf,
                       unsigned* __restrict__ kmax, int pass)
{
  extern __shared__ char sm[];
  char* ph = sm;            // [256 cols][128B] bf16 proj-hi, swizzle ^((col&7)<<4)
  char* pl = sm + 32768;    // proj-lo, same layout
  __shared__ float wred[4];

  int tid = threadIdx.x;
  int w   = tid >> 6;
  int lane= tid & 63;
  int l31 = lane & 31;
  int half= lane >> 5;

  int mode, tile;
  if (pass == 0){
    if (blockIdx.x < 512){ mode = 0; tile = (int)blockIdx.x; }
    else                 { mode = 1; tile = (int)blockIdx.x - 512; }
  } else { mode = 2; tile = (int)blockIdx.x; }
  const float* src = (mode == 0) ? q : k;
  int row0 = tile * 128;
  int row  = row0 + 32*w + l31;

  for (int i = tid; i < 2048; i += 256){
    int rr = i >> 3, c8 = i & 7;
    int off = rr*128 + ((c8*16) ^ ((rr&7)<<4));
    *(uint4*)(ph + off) = *(const uint4*)(pjh + rr*64 + c8*8);
    *(uint4*)(pl + off) = *(const uint4*)(pjl + rr*64 + c8*8);
  }

  bf16x8 ah[4], al[4];
  float dsum = 0.f;
  const float* rp = src + (size_t)row*64;
  #pragma unroll
  for (int ks=0; ks<4; ++ks){
    float4 x0 = *(const float4*)(rp + ks*16 + half*8);
    float4 x1 = *(const float4*)(rp + ks*16 + half*8 + 4);
    float xs[8] = {x0.x,x0.y,x0.z,x0.w,x1.x,x1.y,x1.z,x1.w};
    #pragma unroll
    for (int u=0; u<8; ++u){
      float xv = xs[u];
      dsum += xv*xv;
      unsigned short hi = f2bf(xv);
      float lo = xv - bf2f(hi);
      ah[ks][u] = (short)hi;
      al[ks][u] = (short)f2bf(lo);
    }
  }
  dsum += __shfl_xor(dsum, 32);

  f32x16 acc[8];
  #pragma unroll
  for (int ct=0; ct<8; ++ct){
    #pragma unroll
    for (int r=0; r<16; ++r) acc[ct][r] = 0.f;
  }
  __syncthreads();

  #pragma unroll
  for (int ct=0; ct<8; ++ct){
    int col = ct*32 + l31;
    #pragma unroll
    for (int ks=0; ks<4; ++ks){
      int boff = col*128 + ((ks*32 + half*16) ^ ((col&7)<<4));
      bf16x8 bh = *(const bf16x8*)(ph + boff);
      bf16x8 bl = *(const bf16x8*)(pl + boff);
      acc[ct] = __builtin_amdgcn_mfma_f32_32x32x16_bf16(ah[ks], bh, acc[ct], 0, 0, 0);
      acc[ct] = __builtin_amdgcn_mfma_f32_32x32x16_bf16(al[ks], bh, acc[ct], 0, 0, 0);
      acc[ct] = __builtin_amdgcn_mfma_f32_32x32x16_bf16(ah[ks], bl, acc[ct], 0, 0, 0);
    }
  }

  float rmax[16];
  #pragma unroll
  for (int r=0; r<16; ++r){
    float mx = acc[0][r];
    #pragma unroll
    for (int ct=1; ct<8; ++ct) mx = fmaxf(mx, acc[ct][r]);
    #pragma unroll
    for (int s=1; s<32; s<<=1) mx = fmaxf(mx, __shfl_xor(mx, s));
    rmax[r] = mx;
  }

  if (mode == 1){
    float wm = rmax[0];
    #pragma unroll
    for (int r=1; r<16; ++r) wm = fmaxf(wm, rmax[r]);
    wm = fmaxf(wm, __shfl_xor(wm, 32));
    if (lane == 0) wred[w] = wm;
    __syncthreads();
    if (tid == 0){
      float m4 = fmaxf(fmaxf(wred[0],wred[1]), fmaxf(wred[2],wred[3]));
      atomicMax(kmax, enc_f(m4));
    }
    return;
  }
  float gm = 0.f;
  if (mode == 2) gm = dec_f(*kmax);

  float diagv[16];
  #pragma unroll
  for (int r=0; r<16; ++r){
    int lrow = (r&3) + 8*(r>>2) + 4*half;
    diagv[r] = DIAGC * __shfl(dsum, lrow);
  }

  __syncthreads();
  char* ob = sm;     // [128 rows][512B] ushort
  #pragma unroll
  for (int r=0; r<16; ++r){
    int lrow = 32*w + (r&3) + 8*(r>>2) + 4*half;
    float st = (mode==0) ? rmax[r] : gm;
    float dg = diagv[r];
    #pragma unroll
    for (int ct=0; ct<8; ++ct){
      float val = RATIO * (__expf(acc[ct][r] - dg - st) + KEPS);
      *(ushort_t*)(ob + lrow*512 + (ct*32 + l31)*2) = f2bf(val);
    }
  }
  __syncthreads();
  ushort_t* dst = ((mode==0) ? qf : kf) + (size_t)row0*256;
  for (int i = tid; i < 4096; i += 256)
    *(uint4*)(dst + i*8) = *(const uint4*)(ob + i*16);
}

// K3 (MFMA): per-chunk sums. Sl[cb][m][e] = sum_c kf[c][m]*v[c][e]; Zl[cb][m] = sum_c kf[c][m].
// Operands transposed into LDS: kT[m][c], vT[e][c] bf16, rows 256B, swizzle ^((row&15)<<4).
// Zl via ones-column B fragment (fp32-exact column sums of kf).
__launch_bounds__(256)
__global__ void k_chunk(const ushort_t* __restrict__ kf, const float* __restrict__ v,
                        float* __restrict__ Zl, float* __restrict__ Sl){
  extern __shared__ char sm[];
  char* kT = sm;            // [256 m][256 B]  (c 0..127 bf16)
  char* vT = sm + 65536;    // [64 e][256 B]   (c 0..127 bf16)
  int tid = threadIdx.x;
  int w   = tid >> 6;
  int lane= tid & 63;
  int l31 = lane & 31;
  int half= lane >> 5;
  int bh = blockIdx.x >> 5, j = blockIdx.x & 31;
  int row0 = bh*4096 + j*128;
  int cb = bh*32 + j;

  // stage kT: thread owns column m = tid of kf (reads coalesced across threads)
  {
    const ushort_t* kp = kf + (size_t)row0*256 + tid;
    char* krow = kT + tid*256;
    int swz = (tid & 15) << 4;
    #pragma unroll 16
    for (int c=0; c<128; ++c){
      ushort_t kv = kp[(size_t)c*256];
      *(ushort_t*)(krow + ((c*2) ^ swz)) = kv;
    }
  }
  // stage vT: e = tid&63, c = (tid>>6) + 4u
  {
    int e = tid & 63; int c0 = tid >> 6;
    char* vrow = vT + e*256;
    int swz = (e & 15) << 4;
    #pragma unroll 8
    for (int u=0; u<32; ++u){
      int c = c0 + u*4;
      float vv = v[(size_t)(row0+c)*64 + e];
      *(ushort_t*)(vrow + ((c*2) ^ swz)) = f2bf(vv);
    }
  }
  __syncthreads();

  f32x16 acc[2][2];
  f32x16 accz[2];
  #pragma unroll
  for (int a=0;a<2;++a){
    #pragma unroll
    for (int b=0;b<2;++b){
      #pragma unroll
      for (int r=0;r<16;++r) acc[a][b][r]=0.f;
    }
    #pragma unroll
    for (int r=0;r<16;++r) accz[a][r]=0.f;
  }
  bf16x8 onesf;
  #pragma unroll
  for (int i=0;i<8;++i) onesf[i] = (l31==0) ? (short)0x3F80 : (short)0;

  #pragma unroll
  for (int ks=0; ks<8; ++ks){
    int koff = ks*32 + half*16;
    bf16x8 af[2], bf[2];
    #pragma unroll
    for (int mt=0; mt<2; ++mt){
      int m = (2*w + mt)*32 + l31;
      af[mt] = *(const bf16x8*)(kT + m*256 + (koff ^ ((m&15)<<4)));
    }
    #pragma unroll
    for (int et=0; et<2; ++et){
      int e = et*32 + l31;
      bf[et] = *(const bf16x8*)(vT + e*256 + (koff ^ ((e&15)<<4)));
    }
    #pragma unroll
    for (int mt=0; mt<2; ++mt){
      accz[mt] = __builtin_amdgcn_mfma_f32_32x32x16_bf16(af[mt], onesf, accz[mt], 0, 0, 0);
      #pragma unroll
      for (int et=0; et<2; ++et)
        acc[mt][et] = __builtin_amdgcn_mfma_f32_32x32x16_bf16(af[mt], bf[et], acc[mt][et], 0, 0, 0);
    }
  }

  // store: D col = l31, row = (r&3)+8*(r>>2)+4*half
  #pragma unroll
  for (int mt=0; mt<2; ++mt){
    #pragma unroll
    for (int r=0; r<16; ++r){
      int m = (2*w + mt)*32 + (r&3) + 8*(r>>2) + 4*half;
      #pragma unroll
      for (int et=0; et<2; ++et){
        int e = et*32 + l31;
        Sl[(size_t)cb*16384 + (size_t)m*64 + e] = acc[mt][et][r];
      }
    }
  }
  if (l31 == 0){
    #pragma unroll
    for (int mt=0; mt<2; ++mt){
      #pragma unroll
      for (int r=0; r<16; ++r){
        int m = (2*w + mt)*32 + (r&3) + 8*(r>>2) + 4*half;
        Zl[(size_t)cb*256 + m] = accz[mt][r];
      }
    }
  }
}

// K4: parallel exclusive scan over the 32 chunks. Sl layout [cb][m][e].
__launch_bounds__(256)
__global__ void k_scan(float* __restrict__ Zl, float* __restrict__ Sl,
                       float* __restrict__ outZ, float* __restrict__ outS){
  int t = threadIdx.x;
  int bh = blockIdx.x / 65;
  int s  = blockIdx.x % 65;
  if (s == 64){
    size_t base = (size_t)(bh*32)*256 + t;
    float rz = 0.f;
    #pragma unroll
    for (int j0=0;j0<32;j0+=8){
      float x[8];
      #pragma unroll
      for (int u=0;u<8;++u) x[u] = Zl[base + (size_t)(j0+u)*256];
      #pragma unroll
      for (int u=0;u<8;++u){ Zl[base + (size_t)(j0+u)*256] = rz; rz += x[u]; }
    }
    outZ[(size_t)bh*256 + t] = rz;
  } else {
    size_t base = (size_t)(bh*32)*16384 + (size_t)s*256 + t;
    float rs = 0.f;
    #pragma unroll
    for (int j0=0;j0<32;j0+=8){
      float x[8];
      #pragma unroll
      for (int u=0;u<8;++u) x[u] = Sl[base + (size_t)(j0+u)*16384];
      #pragma unroll
      for (int u=0;u<8;++u){ Sl[base + (size_t)(j0+u)*16384] = rs; rs += x[u]; }
    }
    // outS layout [bh][m][e]; slot s*256+t == m*64+e
    outS[(size_t)bh*16384 + (size_t)s*256 + t] = rs;
  }
}

// K_QZ: qz[row] = sum_m qf[row][m] * (Z0[chunk][m] + eps), fp32 exact.
__launch_bounds__(256)
__global__ void k_qz(const ushort_t* __restrict__ qf, const float* __restrict__ Zp,
                     float* __restrict__ qz){
  __shared__ float z0[256];
  int tid = threadIdx.x;
  int bh = blockIdx.x >> 5, j = blockIdx.x & 31;
  int row0 = bh*4096 + j*128;
  int pb = bh*32 + j;
  z0[tid] = Zp[(size_t)pb*256 + tid] + AEPS;
  __syncthreads();
  int l = tid & 63, w = tid >> 6;
  #pragma unroll
  for (int ri = 0; ri < 4; ++ri){
    int row = ri*32 + w*8 + (l>>3);
    float s = 0.f;
    #pragma unroll
    for (int seg=0; seg<4; ++seg){
      int m = seg*64 + (l&7)*8;
      uint4 u = *(const uint4*)(qf + (size_t)(row0+row)*256 + m);
      float4 za = *(const float4*)&z0[m];
      float4 zb = *(const float4*)&z0[m+4];
      s += bf2f((ushort_t)(u.x&0xffffu))*za.x + bf2f((ushort_t)(u.x>>16))*za.y
         + bf2f((ushort_t)(u.y&0xffffu))*za.z + bf2f((ushort_t)(u.y>>16))*za.w
         + bf2f((ushort_t)(u.z&0xffffu))*zb.x + bf2f((ushort_t)(u.z>>16))*zb.y
         + bf2f((ushort_t)(u.w&0xffffu))*zb.z + bf2f((ushort_t)(u.w>>16))*zb.w;
    }
    s += __shfl_xor(s,1); s += __shfl_xor(s,2); s += __shfl_xor(s,4);
    if ((l&7)==0) qz[(size_t)row0 + row] = s;
  }
}

// K5 (MFMA): per-chunk output.
__launch_bounds__(256)
__global__ void k_out(const ushort_t* __restrict__ qf, const ushort_t* __restrict__ kf,
                      const float* __restrict__ v, const float* __restrict__ Sp,
                      const float* __restrict__ qz, float* __restrict__ outO){
  extern __shared__ char smc[];
  char* Ab  = smc;                 // A_lds bf16 [128][128], rows 256B, swizzle ^((r&15)<<4)
  char* qtb = smc + 32768;         // qt bf16 [128][64], rows 128B, swizzle ^((r&7)<<4)
  char* ktb = smc + 49152;         // kt (phase A) -- aliased by bT after phase A
  char* bTb = smc + 49152;         // bT bf16 [64][64], rows 128B, swizzle ^((e&7)<<4)
  float* rsum = (float*)(smc + 49152 + 8192);  // [128] f32

  int tid = threadIdx.x;
  int w   = tid >> 6;
  int lane= tid & 63;
  int l31 = lane & 31;
  int half= lane >> 5;
  int arow= 32*w + l31;
  int bh = blockIdx.x >> 5, j = blockIdx.x & 31;
  int row0 = bh*4096 + j*128;
  size_t qbase = (size_t)row0*256;
  int pb = bh*32 + j;

  // ---------------- Phase A: A = qf * kf^T (lower triangle only) ----------------
  f32x16 acc[4];
  #pragma unroll
  for (int ct=0;ct<4;++ct){
    #pragma unroll
    for (int r=0;r<16;++r) acc[ct][r] = 0.f;
  }

  for (int m0=0;m0<256;m0+=64){
    __syncthreads();
    #pragma unroll
    for (int u=0;u<4;++u){
      int ci = tid*4+u; int rr = ci>>3, c8 = ci&7;
      int sw = (c8*16) ^ ((rr&7)<<4);
      *(uint4*)(qtb + rr*128 + sw) = *(const uint4*)(qf + qbase + (size_t)rr*256 + m0 + c8*8);
      *(uint4*)(ktb + rr*128 + sw) = *(const uint4*)(kf + qbase + (size_t)rr*256 + m0 + c8*8);
    }
    __syncthreads();
    #pragma unroll
    for (int ks=0;ks<4;++ks){
      bf16x8 af = *(const bf16x8*)(qtb + arow*128 + ((ks*32 + half*16) ^ ((arow&7)<<4)));
      #pragma unroll
      for (int ct=0;ct<4;++ct){
        if (ct <= w){
          int br = ct*32 + l31;
          bf16x8 bfv = *(const bf16x8*)(ktb + br*128 + ((ks*32 + half*16) ^ ((br&7)<<4)));
          acc[ct] = __builtin_amdgcn_mfma_f32_32x32x16_bf16(af, bfv, acc[ct], 0, 0, 0);
        }
      }
    }
  }

  float p[16];
  #pragma unroll
  for (int r=0;r<16;++r) p[r]=0.f;
  #pragma unroll
  for (int ct=0;ct<4;++ct){
    #pragma unroll
    for (int r=0;r<16;++r){
      int grow = 32*w + (r&3) + 8*(r>>2) + 4*half;
      int col  = ct*32 + l31;
      float m = (col <= grow) ? acc[ct][r] : 0.f;
      p[r] += m;
      *(ushort_t*)(Ab + grow*256 + ((col*2) ^ ((grow&15)<<4))) = f2bf(m);
    }
  }
  #pragma unroll
  for (int s=1;s<32;s<<=1){
    #pragma unroll
    for (int r=0;r<16;++r) p[r] += __shfl_xor(p[r], s);
  }
  __syncthreads();
  if (l31 == 0){
    #pragma unroll
    for (int r=0;r<16;++r) rsum[32*w + (r&3) + 8*(r>>2) + 4*half] = p[r];
  }

  // ---------------- Phase B: numer = A*v + qf*S0 ----------------
  f32x16 acc2[2];
  #pragma unroll
  for (int ct=0;ct<2;++ct){
    #pragma unroll
    for (int r=0;r<16;++r) acc2[ct][r] = 0.f;
  }

  for (int kt_i=0; kt_i<6; ++kt_i){
    __syncthreads();
    if (kt_i < 2){
      #pragma unroll
      for (int u=0;u<4;++u){
        int idx = tid*4+u; int rr = idx>>4, c4 = idx&15;
        float4 vv = *(const float4*)&v[(size_t)(row0 + kt_i*64 + rr)*64 + c4*4];
        #pragma unroll
        for (int jj=0;jj<4;++jj){
          int e = c4*4 + jj;
          float val = (jj==0)?vv.x:(jj==1)?vv.y:(jj==2)?vv.z:vv.w;
          *(ushort_t*)(bTb + e*128 + ((rr*2) ^ ((e&7)<<4))) = f2bf(val);
        }
      }
    } else {
      int m0 = (kt_i-2)*64;
      // Sp layout [pb][m][e]: stage bT[e][mm] = bf16(S0[m0+mm][e])
      #pragma unroll
      for (int u=0;u<4;++u){
        int idx = u*256 + tid; int mm = idx>>4, e4 = idx&15;
        float4 sv = *(const float4*)&Sp[(size_t)pb*16384 + (size_t)(m0+mm)*64 + e4*4];
        #pragma unroll
        for (int jj=0;jj<4;++jj){
          int e = e4*4 + jj;
          float val = (jj==0)?sv.x:(jj==1)?sv.y:(jj==2)?sv.z:sv.w;
          *(ushort_t*)(bTb + e*128 + ((mm*2) ^ ((e&7)<<4))) = f2bf(val);
        }
      }
      #pragma unroll
      for (int u=0;u<4;++u){
        int ci = tid*4+u; int rr = ci>>3, c8 = ci&7;
        *(uint4*)(qtb + rr*128 + ((c8*16) ^ ((rr&7)<<4))) =
            *(const uint4*)(qf + qbase + (size_t)rr*256 + m0 + c8*8);
      }
    }
    __syncthreads();
    #pragma unroll
    for (int ks=0;ks<4;++ks){
      bf16x8 af;
      bool doit = true;
      if (kt_i < 2){
        doit = (kt_i*64 + ks*16 <= 32*w + 31);
        if (doit)
          af = *(const bf16x8*)(Ab + arow*256 + ((kt_i*128 + ks*32 + half*16) ^ ((arow&15)<<4)));
      } else {
        af = *(const bf16x8*)(qtb + arow*128 + ((ks*32 + half*16) ^ ((arow&7)<<4)));
      }
      if (doit){
        #pragma unroll
        for (int ct2=0;ct2<2;++ct2){
          int br = ct2*32 + l31;
          bf16x8 bfv = *(const bf16x8*)(bTb + br*128 + ((ks*32 + half*16) ^ ((br&7)<<4)));
          acc2[ct2] = __builtin_amdgcn_mfma_f32_32x32x16_bf16(af, bfv, acc2[ct2], 0, 0, 0);
        }
      }
    }
  }

  __syncthreads();
  if (tid < 128) rsum[tid] = 1.0f / (rsum[tid] + qz[(size_t)row0 + tid]);
  __syncthreads();
  float dvv[16];
  #pragma unroll
  for (int r=0;r<16;++r) dvv[r] = rsum[32*w + (r&3) + 8*(r>>2) + 4*half];
  #pragma unroll
  for (int ct2=0;ct2<2;++ct2){
    #pragma unroll
    for (int r=0;r<16;++r){
      int qrow = 32*w + (r&3) + 8*(r>>2) + 4*half;
      int e = ct2*32 + l31;
      outO[(size_t)(row0+qrow)*64 + e] = acc2[ct2][r] * dvv[r];
    }
  }
}

extern "C" void kernel_launch(void* const* d_in, const int* in_sizes, int n_in,
                              void* d_out, int out_size, void* d_ws, size_t ws_size,
                              hipStream_t stream){
  (void)in_sizes; (void)n_in; (void)out_size; (void)ws_size;
  const float* q    = (const float*)d_in[0];
  const float* k    = (const float*)d_in[1];
  const float* v    = (const float*)d_in[2];
  const float* proj = (const float*)d_in[3];

  char* ws = (char*)d_ws;
  unsigned* kmax = (unsigned*)ws;                                   // 256 B slot
  ushort_t* pjh  = (ushort_t*)(ws + 256);                           // 32768 B
  ushort_t* pjl  = (ushort_t*)(ws + 256 + 32768);                   // 32768 B
  ushort_t* qf   = (ushort_t*)(ws + 65792);                         // 33554432 B
  ushort_t* kf   = (ushort_t*)(ws + 65792 + 33554432);              // 33554432 B
  float*    Zl   = (float*)(ws + 65792 + 67108864);                 // 524288 B
  float*    Sl   = (float*)(ws + 65792 + 67108864 + 524288);        // 33554432 B
  float*    qzb  = (float*)(ws + 65792 + 67108864 + 524288 + 33554432); // 262144 B

  float* outO = (float*)d_out;
  float* outZ = outO + (size_t)2*8*4096*64;
  float* outS = outZ + 2*8*256;

  hipFuncSetAttribute((const void*)k_feat,  hipFuncAttributeMaxDynamicSharedMemorySize, 65536);
  hipFuncSetAttribute((const void*)k_chunk, hipFuncAttributeMaxDynamicSharedMemorySize, 81920);
  hipFuncSetAttribute((const void*)k_out,   hipFuncAttributeMaxDynamicSharedMemorySize, 65536);

  k_prep <<<1,      256, 0, stream>>>(proj, pjh, pjl, kmax);
  k_feat <<<1024,   256, 65536, stream>>>(q, k, pjh, pjl, qf, kf, kmax, 0);
  k_feat <<<512,    256, 65536, stream>>>(q, k, pjh, pjl, qf, kf, kmax, 1);
  k_chunk<<<512,    256, 81920, stream>>>(kf, v, Zl, Sl);
  k_scan <<<16*65,  256, 0, stream>>>(Zl, Sl, outZ, outS);
  k_qz   <<<512,    256, 0, stream>>>(qf, Zl, qzb);
  k_out  <<<512,    256, 65536, stream>>>(qf, kf, v, Sl, qzb, outO);
}

// Round 6
// 106.605 us; speedup vs baseline: 5.9361x; 1.3064x over previous
//
#include <hip/hip_runtime.h>

typedef unsigned short ushort_t;
typedef __attribute__((ext_vector_type(8))) short bf16x8;
typedef __attribute__((ext_vector_type(8))) _Float16 f16x8;
typedef __attribute__((ext_vector_type(16))) float f32x16;

#define NORMC 0.35355339059327373f   // 64^-0.25
#define DIAGC 0.0625f                // 0.5 * 64^-0.5
#define RATIO 0.0625f                // 256^-0.5
#define KEPS  1e-4f
#define AEPS  1e-6f
#define KAPPA (RATIO*KEPS)

__device__ __forceinline__ unsigned short f2bf(float f){
  unsigned u = __float_as_uint(f);
  unsigned r = (u + 0x7FFFu + ((u >> 16) & 1u)) >> 16;  // RNE
  return (unsigned short)r;
}
__device__ __forceinline__ float bf2f(unsigned short h){
  return __uint_as_float(((unsigned)h) << 16);
}
__device__ __forceinline__ unsigned enc_f(float f){
  unsigned u = __float_as_uint(f);
  return (u & 0x80000000u) ? ~u : (u | 0x80000000u);
}
__device__ __forceinline__ float dec_f(unsigned e){
  unsigned b = (e & 0x80000000u) ? (e ^ 0x80000000u) : ~e;
  return __uint_as_float(b);
}
__device__ __forceinline__ unsigned short h2u(_Float16 h){
  union { _Float16 h; unsigned short u; } c; c.h = h; return c.u;
}
__device__ __forceinline__ unsigned pk2h(float a, float b){
  return (unsigned)h2u((_Float16)a) | ((unsigned)h2u((_Float16)b) << 16);
}
// corrected-kf transform: bf16(alpha*bf2f(x)+kappa) for both halves of a packed word
__device__ __forceinline__ unsigned cvt2(unsigned wrd, float alpha){
  float lo = bf2f((ushort_t)(wrd & 0xffffu));
  float hi = bf2f((ushort_t)(wrd >> 16));
  return (unsigned)f2bf(fmaf(alpha, lo, KAPPA)) |
         ((unsigned)f2bf(fmaf(alpha, hi, KAPPA)) << 16);
}

// K0: proj -> fp16 (NORMC-scaled), layout [m][d]; init global-max slot
__global__ void k_prep(const float* __restrict__ proj, ushort_t* __restrict__ pjh,
                       unsigned* __restrict__ kmax){
  int t = threadIdx.x;   // m
  if (t == 0) *kmax = 0u;
  for (int d = 0; d < 64; ++d){
    float val = NORMC * proj[t*64 + d];
    pjh[t*64 + d] = h2u((_Float16)val);
  }
}

// K1 (fused, MFMA fp16 2-term): blocks 0..511 -> q rows (store qf, row-max stab);
// blocks 512..1023 -> k rows (store kfpre = exp(dash-diag-lm_chunk), lm[], atomicMax gm).
// LDS: Bp  proj fp16 frag-packed [ct4|ks4*... ] 32KB; Xh/Xl x fp16 frag-packed 16KB each;
//      dsm f32[128]; wred f32[4].
__launch_bounds__(256, 2)
__global__ void k_feat(const float* __restrict__ q, const float* __restrict__ k,
                       const ushort_t* __restrict__ pjh,
                       ushort_t* __restrict__ qf, ushort_t* __restrict__ kfp,
                       unsigned* __restrict__ kmax, float* __restrict__ lmArr)
{
  extern __shared__ char sm[];
  char* Bp = sm;                       // 32768: off = (((ct*4+ks)*2+half)*32 + l31)*16
  char* Xh = sm + 32768;               // 16384: off = (((w*4+ks)*2+half)*32 + l31)*16
  char* Xl = sm + 49152;               // 16384
  float* dsm  = (float*)(sm + 65536);  // [128]
  float* wred = (float*)(sm + 66048);  // [4]

  int tid = threadIdx.x;
  int w   = tid >> 6;
  int lane= tid & 63;
  int l31 = lane & 31;
  int half= lane >> 5;

  bool isQ = (blockIdx.x < 512);
  int tile = isQ ? (int)blockIdx.x : (int)blockIdx.x - 512;
  const float* src = isQ ? q : k;
  int row0 = tile * 128;

  // stage proj frags (coalesced)
  for (int i = tid; i < 2048; i += 256){
    int m = i >> 3, c8 = i & 7;
    int off = ((((m>>5)*4 + (c8>>1))*2 + (c8&1))*32 + (m&31))*16;
    *(uint4*)(Bp + off) = *(const uint4*)(pjh + m*64 + c8*8);
  }
  // stage x frags (coalesced float4 -> fp16 hi/lo), per-row sum(x^2)
  #pragma unroll
  for (int it = 0; it < 8; ++it){
    int g = it*256 + tid;
    int row = g >> 4, c4 = g & 15;
    float4 xv = *(const float4*)(src + (size_t)(row0+row)*64 + c4*4);
    _Float16 h0=(_Float16)xv.x, h1=(_Float16)xv.y, h2=(_Float16)xv.z, h3=(_Float16)xv.w;
    float l0 = xv.x-(float)h0, l1 = xv.y-(float)h1, l2 = xv.z-(float)h2, l3 = xv.w-(float)h3;
    int off = ((((row>>5)*4 + (c4>>2))*2 + ((c4>>1)&1))*32 + (row&31))*16 + (c4&1)*8;
    uint2 ph; ph.x = (unsigned)h2u(h0)|((unsigned)h2u(h1)<<16);
              ph.y = (unsigned)h2u(h2)|((unsigned)h2u(h3)<<16);
    uint2 pl; pl.x = pk2h(l0,l1); pl.y = pk2h(l2,l3);
    *(uint2*)(Xh + off) = ph;
    *(uint2*)(Xl + off) = pl;
    float ssq = xv.x*xv.x + xv.y*xv.y + xv.z*xv.z + xv.w*xv.w;
    ssq += __shfl_xor(ssq, 1); ssq += __shfl_xor(ssq, 2);
    ssq += __shfl_xor(ssq, 4); ssq += __shfl_xor(ssq, 8);
    if ((tid & 15) == 0) dsm[row] = ssq;
  }
  __syncthreads();

  f16x8 ah[4], al[4];
  #pragma unroll
  for (int ks = 0; ks < 4; ++ks){
    int offa = (((w*4+ks)*2+half)*32 + l31)*16;
    ah[ks] = *(const f16x8*)(Xh + offa);
    al[ks] = *(const f16x8*)(Xl + offa);
  }
  f32x16 acc[8];
  #pragma unroll
  for (int ct=0; ct<8; ++ct){
    #pragma unroll
    for (int r=0; r<16; ++r) acc[ct][r] = 0.f;
  }
  #pragma unroll
  for (int ks = 0; ks < 4; ++ks){
    f16x8 bv[8];
    #pragma unroll
    for (int ct=0; ct<8; ++ct)
      bv[ct] = *(const f16x8*)(Bp + (((ct*4+ks)*2+half)*32 + l31)*16);
    #pragma unroll
    for (int ct=0; ct<8; ++ct)
      acc[ct] = __builtin_amdgcn_mfma_f32_32x32x16_f16(ah[ks], bv[ct], acc[ct], 0, 0, 0);
    #pragma unroll
    for (int ct=0; ct<8; ++ct)
      acc[ct] = __builtin_amdgcn_mfma_f32_32x32x16_f16(al[ks], bv[ct], acc[ct], 0, 0, 0);
  }

  // per-row max over 256 cols (reduce over 32 lanes)
  float rmax[16];
  #pragma unroll
  for (int r=0; r<16; ++r){
    float mx = acc[0][r];
    #pragma unroll
    for (int ct=1; ct<8; ++ct) mx = fmaxf(mx, acc[ct][r]);
    #pragma unroll
    for (int s=1; s<32; s<<=1) mx = fmaxf(mx, __shfl_xor(mx, s));
    rmax[r] = mx;
  }
  if (!isQ){
    float wm = rmax[0];
    #pragma unroll
    for (int r=1; r<16; ++r) wm = fmaxf(wm, rmax[r]);
    wm = fmaxf(wm, __shfl_xor(wm, 32));
    if (lane == 0) wred[w] = wm;
  }
  __syncthreads();   // MFMA LDS reads done; wred visible

  float lmb = 0.f;
  if (!isQ){
    lmb = fmaxf(fmaxf(wred[0], wred[1]), fmaxf(wred[2], wred[3]));
    if (tid == 0){
      lmArr[tile] = lmb;
      atomicMax(kmax, enc_f(lmb));
    }
  }
  float dgv[16];
  #pragma unroll
  for (int r=0; r<16; ++r)
    dgv[r] = DIAGC * dsm[32*w + (r&3) + 8*(r>>2) + 4*half];

  char* ob = sm;   // [128 rows][512B], overwrites Bp/Xh/Xl (safe after barrier)
  #pragma unroll
  for (int r=0; r<16; ++r){
    int lrow = 32*w + (r&3) + 8*(r>>2) + 4*half;
    float st = isQ ? rmax[r] : lmb;
    float dg = dgv[r];
    #pragma unroll
    for (int ct=0; ct<8; ++ct){
      float e = __expf(acc[ct][r] - dg - st);
      float val = isQ ? RATIO*(e + KEPS) : e;
      *(ushort_t*)(ob + lrow*512 + (ct*32 + l31)*2) = f2bf(val);
    }
  }
  __syncthreads();
  ushort_t* dst = (isQ ? qf : kfp) + (size_t)row0*256;
  for (int i = tid; i < 4096; i += 256)
    *(uint4*)(dst + i*8) = *(const uint4*)(ob + i*16);
}

// K3 (MFMA): per-chunk sums on corrected kf = alpha*kfpre + kappa (applied at staging).
// Sl[cb][m][e] = sum_c kf*v; Zl[cb][m] = sum_c kf (ones-column B).
__launch_bounds__(256)
__global__ void k_chunk(const ushort_t* __restrict__ kfp, const float* __restrict__ v,
                        float* __restrict__ Zl, float* __restrict__ Sl,
                        const float* __restrict__ lmArr, const unsigned* __restrict__ kmax){
  extern __shared__ char sm[];
  char* kT = sm;            // [256 m][256 B]  (c 0..127 bf16)
  char* vT = sm + 65536;    // [64 e][256 B]
  int tid = threadIdx.x;
  int w   = tid >> 6;
  int lane= tid & 63;
  int l31 = lane & 31;
  int half= lane >> 5;
  int bh = blockIdx.x >> 5, j = blockIdx.x & 31;
  int row0 = bh*4096 + j*128;
  int cb = bh*32 + j;

  float gmv = dec_f(*kmax);
  float alpha = RATIO * __expf(lmArr[cb] - gmv);

  {
    const ushort_t* kp = kfp + (size_t)row0*256 + tid;
    char* krow = kT + tid*256;
    int swz = (tid & 15) << 4;
    #pragma unroll 16
    for (int c=0; c<128; ++c){
      float val = fmaf(alpha, bf2f(kp[(size_t)c*256]), KAPPA);
      *(ushort_t*)(krow + ((c*2) ^ swz)) = f2bf(val);
    }
  }
  {
    int e = tid & 63; int c0 = tid >> 6;
    char* vrow = vT + e*256;
    int swz = (e & 15) << 4;
    #pragma unroll 8
    for (int u=0; u<32; ++u){
      int c = c0 + u*4;
      float vv = v[(size_t)(row0+c)*64 + e];
      *(ushort_t*)(vrow + ((c*2) ^ swz)) = f2bf(vv);
    }
  }
  __syncthreads();

  f32x16 acc[2][2];
  f32x16 accz[2];
  #pragma unroll
  for (int a=0;a<2;++a){
    #pragma unroll
    for (int b=0;b<2;++b){
      #pragma unroll
      for (int r=0;r<16;++r) acc[a][b][r]=0.f;
    }
    #pragma unroll
    for (int r=0;r<16;++r) accz[a][r]=0.f;
  }
  bf16x8 onesf;
  #pragma unroll
  for (int i=0;i<8;++i) onesf[i] = (l31==0) ? (short)0x3F80 : (short)0;

  #pragma unroll
  for (int ks=0; ks<8; ++ks){
    int koff = ks*32 + half*16;
    bf16x8 af[2], bf[2];
    #pragma unroll
    for (int mt=0; mt<2; ++mt){
      int m = (2*w + mt)*32 + l31;
      af[mt] = *(const bf16x8*)(kT + m*256 + (koff ^ ((m&15)<<4)));
    }
    #pragma unroll
    for (int et=0; et<2; ++et){
      int e = et*32 + l31;
      bf[et] = *(const bf16x8*)(vT + e*256 + (koff ^ ((e&15)<<4)));
    }
    #pragma unroll
    for (int mt=0; mt<2; ++mt){
      accz[mt] = __builtin_amdgcn_mfma_f32_32x32x16_bf16(af[mt], onesf, accz[mt], 0, 0, 0);
      #pragma unroll
      for (int et=0; et<2; ++et)
        acc[mt][et] = __builtin_amdgcn_mfma_f32_32x32x16_bf16(af[mt], bf[et], acc[mt][et], 0, 0, 0);
    }
  }

  #pragma unroll
  for (int mt=0; mt<2; ++mt){
    #pragma unroll
    for (int r=0; r<16; ++r){
      int m = (2*w + mt)*32 + (r&3) + 8*(r>>2) + 4*half;
      #pragma unroll
      for (int et=0; et<2; ++et){
        int e = et*32 + l31;
        Sl[(size_t)cb*16384 + (size_t)m*64 + e] = acc[mt][et][r];
      }
    }
  }
  if (l31 == 0){
    #pragma unroll
    for (int mt=0; mt<2; ++mt){
      #pragma unroll
      for (int r=0; r<16; ++r){
        int m = (2*w + mt)*32 + (r&3) + 8*(r>>2) + 4*half;
        Zl[(size_t)cb*256 + m] = accz[mt][r];
      }
    }
  }
}

// K4: parallel exclusive scan over the 32 chunks. Sl layout [cb][m][e].
__launch_bounds__(256)
__global__ void k_scan(float* __restrict__ Zl, float* __restrict__ Sl,
                       float* __restrict__ outZ, float* __restrict__ outS){
  int t = threadIdx.x;
  int bh = blockIdx.x / 65;
  int s  = blockIdx.x % 65;
  if (s == 64){
    size_t base = (size_t)(bh*32)*256 + t;
    float rz = 0.f;
    #pragma unroll
    for (int j0=0;j0<32;j0+=8){
      float x[8];
      #pragma unroll
      for (int u=0;u<8;++u) x[u] = Zl[base + (size_t)(j0+u)*256];
      #pragma unroll
      for (int u=0;u<8;++u){ Zl[base + (size_t)(j0+u)*256] = rz; rz += x[u]; }
    }
    outZ[(size_t)bh*256 + t] = rz;
  } else {
    size_t base = (size_t)(bh*32)*16384 + (size_t)s*256 + t;
    float rs = 0.f;
    #pragma unroll
    for (int j0=0;j0<32;j0+=8){
      float x[8];
      #pragma unroll
      for (int u=0;u<8;++u) x[u] = Sl[base + (size_t)(j0+u)*16384];
      #pragma unroll
      for (int u=0;u<8;++u){ Sl[base + (size_t)(j0+u)*16384] = rs; rs += x[u]; }
    }
    outS[(size_t)bh*16384 + (size_t)s*256 + t] = rs;
  }
}

// K_QZ: qz[row] = sum_m qf[row][m] * (Z0[chunk][m] + eps), fp32 exact.
__launch_bounds__(256)
__global__ void k_qz(const ushort_t* __restrict__ qf, const float* __restrict__ Zp,
                     float* __restrict__ qz){
  __shared__ float z0[256];
  int tid = threadIdx.x;
  int bh = blockIdx.x >> 5, j = blockIdx.x & 31;
  int row0 = bh*4096 + j*128;
  int pb = bh*32 + j;
  z0[tid] = Zp[(size_t)pb*256 + tid] + AEPS;
  __syncthreads();
  int l = tid & 63, w = tid >> 6;
  #pragma unroll
  for (int ri = 0; ri < 4; ++ri){
    int row = ri*32 + w*8 + (l>>3);
    float s = 0.f;
    #pragma unroll
    for (int seg=0; seg<4; ++seg){
      int m = seg*64 + (l&7)*8;
      uint4 u = *(const uint4*)(qf + (size_t)(row0+row)*256 + m);
      float4 za = *(const float4*)&z0[m];
      float4 zb = *(const float4*)&z0[m+4];
      s += bf2f((ushort_t)(u.x&0xffffu))*za.x + bf2f((ushort_t)(u.x>>16))*za.y
         + bf2f((ushort_t)(u.y&0xffffu))*za.z + bf2f((ushort_t)(u.y>>16))*za.w
         + bf2f((ushort_t)(u.z&0xffffu))*zb.x + bf2f((ushort_t)(u.z>>16))*zb.y
         + bf2f((ushort_t)(u.w&0xffffu))*zb.z + bf2f((ushort_t)(u.w>>16))*zb.w;
    }
    s += __shfl_xor(s,1); s += __shfl_xor(s,2); s += __shfl_xor(s,4);
    if ((l&7)==0) qz[(size_t)row0 + row] = s;
  }
}

// K5 (MFMA): per-chunk output. kf corrected at ktb staging.
__launch_bounds__(256)
__global__ void k_out(const ushort_t* __restrict__ qf, const ushort_t* __restrict__ kfp,
                      const float* __restrict__ v, const float* __restrict__ Sp,
                      const float* __restrict__ qz, float* __restrict__ outO,
                      const float* __restrict__ lmArr, const unsigned* __restrict__ kmax){
  extern __shared__ char smc[];
  char* Ab  = smc;                 // A_lds bf16 [128][128], rows 256B, swizzle ^((r&15)<<4)
  char* qtb = smc + 32768;         // qt bf16 [128][64], rows 128B, swizzle ^((r&7)<<4)
  char* ktb = smc + 49152;         // kt (phase A) -- aliased by bT after phase A
  char* bTb = smc + 49152;         // bT bf16 [64][64], rows 128B, swizzle ^((e&7)<<4)
  float* rsum = (float*)(smc + 49152 + 8192);  // [128] f32

  int tid = threadIdx.x;
  int w   = tid >> 6;
  int lane= tid & 63;
  int l31 = lane & 31;
  int half= lane >> 5;
  int arow= 32*w + l31;
  int bh = blockIdx.x >> 5, j = blockIdx.x & 31;
  int row0 = bh*4096 + j*128;
  size_t qbase = (size_t)row0*256;
  int pb = bh*32 + j;

  float gmv = dec_f(*kmax);
  float alpha = RATIO * __expf(lmArr[pb] - gmv);

  // ---------------- Phase A: A = qf * kf^T (lower triangle only) ----------------
  f32x16 acc[4];
  #pragma unroll
  for (int ct=0;ct<4;++ct){
    #pragma unroll
    for (int r=0;r<16;++r) acc[ct][r] = 0.f;
  }

  for (int m0=0;m0<256;m0+=64){
    __syncthreads();
    #pragma unroll
    for (int u=0;u<4;++u){
      int ci = tid*4+u; int rr = ci>>3, c8 = ci&7;
      int sw = (c8*16) ^ ((rr&7)<<4);
      *(uint4*)(qtb + rr*128 + sw) = *(const uint4*)(qf + qbase + (size_t)rr*256 + m0 + c8*8);
      uint4 rk = *(const uint4*)(kfp + qbase + (size_t)rr*256 + m0 + c8*8);
      uint4 ck; ck.x = cvt2(rk.x, alpha); ck.y = cvt2(rk.y, alpha);
                ck.z = cvt2(rk.z, alpha); ck.w = cvt2(rk.w, alpha);
      *(uint4*)(ktb + rr*128 + sw) = ck;
    }
    __syncthreads();
    #pragma unroll
    for (int ks=0;ks<4;++ks){
      bf16x8 af = *(const bf16x8*)(qtb + arow*128 + ((ks*32 + half*16) ^ ((arow&7)<<4)));
      #pragma unroll
      for (int ct=0;ct<4;++ct){
        if (ct <= w){
          int br = ct*32 + l31;
          bf16x8 bfv = *(const bf16x8*)(ktb + br*128 + ((ks*32 + half*16) ^ ((br&7)<<4)));
          acc[ct] = __builtin_amdgcn_mfma_f32_32x32x16_bf16(af, bfv, acc[ct], 0, 0, 0);
        }
      }
    }
  }

  float p[16];
  #pragma unroll
  for (int r=0;r<16;++r) p[r]=0.f;
  #pragma unroll
  for (int ct=0;ct<4;++ct){
    #pragma unroll
    for (int r=0;r<16;++r){
      int grow = 32*w + (r&3) + 8*(r>>2) + 4*half;
      int col  = ct*32 + l31;
      float m = (col <= grow) ? acc[ct][r] : 0.f;
      p[r] += m;
      *(ushort_t*)(Ab + grow*256 + ((col*2) ^ ((grow&15)<<4))) = f2bf(m);
    }
  }
  #pragma unroll
  for (int s=1;s<32;s<<=1){
    #pragma unroll
    for (int r=0;r<16;++r) p[r] += __shfl_xor(p[r], s);
  }
  __syncthreads();
  if (l31 == 0){
    #pragma unroll
    for (int r=0;r<16;++r) rsum[32*w + (r&3) + 8*(r>>2) + 4*half] = p[r];
  }

  // ---------------- Phase B: numer = A*v + qf*S0 ----------------
  f32x16 acc2[2];
  #pragma unroll
  for (int ct=0;ct<2;++ct){
    #pragma unroll
    for (int r=0;r<16;++r) acc2[ct][r] = 0.f;
  }

  for (int kt_i=0; kt_i<6; ++kt_i){
    __syncthreads();
    if (kt_i < 2){
      #pragma unroll
      for (int u=0;u<4;++u){
        int idx = tid*4+u; int rr = idx>>4, c4 = idx&15;
        float4 vv = *(const float4*)&v[(size_t)(row0 + kt_i*64 + rr)*64 + c4*4];
        #pragma unroll
        for (int jj=0;jj<4;++jj){
          int e = c4*4 + jj;
          float val = (jj==0)?vv.x:(jj==1)?vv.y:(jj==2)?vv.z:vv.w;
          *(ushort_t*)(bTb + e*128 + ((rr*2) ^ ((e&7)<<4))) = f2bf(val);
        }
      }
    } else {
      int m0 = (kt_i-2)*64;
      // Sp layout [pb][m][e]: stage bT[e][mm] = bf16(S0[m0+mm][e])
      #pragma unroll
      for (int u=0;u<4;++u){
        int idx = u*256 + tid; int mm = idx>>4, e4 = idx&15;
        float4 sv = *(const float4*)&Sp[(size_t)pb*16384 + (size_t)(m0+mm)*64 + e4*4];
        #pragma unroll
        for (int jj=0;jj<4;++jj){
          int e = e4*4 + jj;
          float val = (jj==0)?sv.x:(jj==1)?sv.y:(jj==2)?sv.z:sv.w;
          *(ushort_t*)(bTb + e*128 + ((mm*2) ^ ((e&7)<<4))) = f2bf(val);
        }
      }
      #pragma unroll
      for (int u=0;u<4;++u){
        int ci = tid*4+u; int rr = ci>>3, c8 = ci&7;
        *(uint4*)(qtb + rr*128 + ((c8*16) ^ ((rr&7)<<4))) =
            *(const uint4*)(qf + qbase + (size_t)rr*256 + m0 + c8*8);
      }
    }
    __syncthreads();
    #pragma unroll
    for (int ks=0;ks<4;++ks){
      bf16x8 af;
      bool doit = true;
      if (kt_i < 2){
        doit = (kt_i*64 + ks*16 <= 32*w + 31);
        if (doit)
          af = *(const bf16x8*)(Ab + arow*256 + ((kt_i*128 + ks*32 + half*16) ^ ((arow&15)<<4)));
      } else {
        af = *(const bf16x8*)(qtb + arow*128 + ((ks*32 + half*16) ^ ((arow&7)<<4)));
      }
      if (doit){
        #pragma unroll
        for (int ct2=0;ct2<2;++ct2){
          int br = ct2*32 + l31;
          bf16x8 bfv = *(const bf16x8*)(bTb + br*128 + ((ks*32 + half*16) ^ ((br&7)<<4)));
          acc2[ct2] = __builtin_amdgcn_mfma_f32_32x32x16_bf16(af, bfv, acc2[ct2], 0, 0, 0);
        }
      }
    }
  }

  __syncthreads();
  if (tid < 128) rsum[tid] = 1.0f / (rsum[tid] + qz[(size_t)row0 + tid]);
  __syncthreads();
  float dvv[16];
  #pragma unroll
  for (int r=0;r<16;++r) dvv[r] = rsum[32*w + (r&3) + 8*(r>>2) + 4*half];
  #pragma unroll
  for (int ct2=0;ct2<2;++ct2){
    #pragma unroll
    for (int r=0;r<16;++r){
      int qrow = 32*w + (r&3) + 8*(r>>2) + 4*half;
      int e = ct2*32 + l31;
      outO[(size_t)(row0+qrow)*64 + e] = acc2[ct2][r] * dvv[r];
    }
  }
}

extern "C" void kernel_launch(void* const* d_in, const int* in_sizes, int n_in,
                              void* d_out, int out_size, void* d_ws, size_t ws_size,
                              hipStream_t stream){
  (void)in_sizes; (void)n_in; (void)out_size; (void)ws_size;
  const float* q    = (const float*)d_in[0];
  const float* k    = (const float*)d_in[1];
  const float* v    = (const float*)d_in[2];
  const float* proj = (const float*)d_in[3];

  char* ws = (char*)d_ws;
  unsigned* kmax = (unsigned*)ws;                                   // @0
  float*    lmA  = (float*)(ws + 256);                              // 2048 B
  ushort_t* pjh  = (ushort_t*)(ws + 4096);                          // 32768 B
  ushort_t* qf   = (ushort_t*)(ws + 65792);                         // 33554432 B
  ushort_t* kfp  = (ushort_t*)(ws + 65792 + 33554432);              // 33554432 B
  float*    Zl   = (float*)(ws + 65792 + 67108864);                 // 524288 B
  float*    Sl   = (float*)(ws + 65792 + 67108864 + 524288);        // 33554432 B
  float*    qzb  = (float*)(ws + 65792 + 67108864 + 524288 + 33554432); // 262144 B

  float* outO = (float*)d_out;
  float* outZ = outO + (size_t)2*8*4096*64;
  float* outS = outZ + 2*8*256;

  hipFuncSetAttribute((const void*)k_feat,  hipFuncAttributeMaxDynamicSharedMemorySize, 66560);
  hipFuncSetAttribute((const void*)k_chunk, hipFuncAttributeMaxDynamicSharedMemorySize, 81920);
  hipFuncSetAttribute((const void*)k_out,   hipFuncAttributeMaxDynamicSharedMemorySize, 65536);

  k_prep <<<1,      256, 0, stream>>>(proj, pjh, kmax);
  k_feat <<<1024,   256, 66560, stream>>>(q, k, pjh, qf, kfp, kmax, lmA);
  k_chunk<<<512,    256, 81920, stream>>>(kfp, v, Zl, Sl, lmA, kmax);
  k_scan <<<16*65,  256, 0, stream>>>(Zl, Sl, outZ, outS);
  k_qz   <<<512,    256, 0, stream>>>(qf, Zl, qzb);
  k_out  <<<512,    256, 65536, stream>>>(qf, kfp, v, Sl, qzb, outO, lmA, kmax);
}

// Round 7
// 93.905 us; speedup vs baseline: 6.7389x; 1.1352x over previous
//
#include <hip/hip_runtime.h>

typedef unsigned short ushort_t;
typedef __attribute__((ext_vector_type(8))) short bf16x8;
typedef __attribute__((ext_vector_type(8))) _Float16 f16x8;
typedef __attribute__((ext_vector_type(16))) float f32x16;

#define NORMC 0.35355339059327373f   // 64^-0.25
#define DIAGC 0.0625f                // 0.5 * 64^-0.5
#define RATIO 0.0625f                // 256^-0.5
#define KEPS  1e-4f
#define AEPS  1e-6f
#define KAPPA (RATIO*KEPS)

__device__ __forceinline__ unsigned short f2bf(float f){
  unsigned u = __float_as_uint(f);
  unsigned r = (u + 0x7FFFu + ((u >> 16) & 1u)) >> 16;  // RNE
  return (unsigned short)r;
}
__device__ __forceinline__ float bf2f(unsigned short h){
  return __uint_as_float(((unsigned)h) << 16);
}
__device__ __forceinline__ unsigned enc_f(float f){
  unsigned u = __float_as_uint(f);
  return (u & 0x80000000u) ? ~u : (u | 0x80000000u);
}
__device__ __forceinline__ float dec_f(unsigned e){
  unsigned b = (e & 0x80000000u) ? (e ^ 0x80000000u) : ~e;
  return __uint_as_float(b);
}
__device__ __forceinline__ unsigned short h2u(_Float16 h){
  union { _Float16 h; unsigned short u; } c; c.h = h; return c.u;
}
__device__ __forceinline__ unsigned pk2h(float a, float b){
  return (unsigned)h2u((_Float16)a) | ((unsigned)h2u((_Float16)b) << 16);
}
// corrected-kf transform: bf16(alpha*bf2f(x)+kappa) for both halves of a packed word
__device__ __forceinline__ unsigned cvt2(unsigned wrd, float alpha){
  float lo = bf2f((ushort_t)(wrd & 0xffffu));
  float hi = bf2f((ushort_t)(wrd >> 16));
  return (unsigned)f2bf(fmaf(alpha, lo, KAPPA)) |
         ((unsigned)f2bf(fmaf(alpha, hi, KAPPA)) << 16);
}

// K0: proj -> fp16 (NORMC-scaled), layout [m][d]; init global-max slot
__global__ void k_prep(const float* __restrict__ proj, ushort_t* __restrict__ pjh,
                       unsigned* __restrict__ kmax){
  int t = threadIdx.x;   // m
  if (t == 0) *kmax = 0u;
  for (int d = 0; d < 64; ++d){
    float val = NORMC * proj[t*64 + d];
    pjh[t*64 + d] = h2u((_Float16)val);
  }
}

// K1 (fused, MFMA fp16 2-term), 8 waves: wave w -> rows 32*(w&3), cols 128*(w>>2).
// blocks 0..511 -> q (store qf, row-max stab); 512..1023 -> k (store kfpre, lm, atomicMax gm)
__launch_bounds__(512, 4)
__global__ void k_feat(const float* __restrict__ q, const float* __restrict__ k,
                       const ushort_t* __restrict__ pjh,
                       ushort_t* __restrict__ qf, ushort_t* __restrict__ kfp,
                       unsigned* __restrict__ kmax, float* __restrict__ lmArr)
{
  extern __shared__ char sm[];
  char* Bp = sm;                        // 32768: 64 regions x 32 slots x 16B, slot ^= (rgn&7)<<2
  char* Xh = sm + 32768;                // 16384: 32 regions
  char* Xl = sm + 49152;                // 16384
  float* dsm  = (float*)(sm + 65536);   // [128]
  float* rmx  = (float*)(sm + 66048);   // [2][128]
  float* wred = (float*)(sm + 67072);   // [8]

  int tid = threadIdx.x;
  int w   = tid >> 6;
  int wr  = w & 3;       // row group
  int wc  = w >> 2;      // col half
  int lane= tid & 63;
  int l31 = lane & 31;
  int half= lane >> 5;

  bool isQ = (blockIdx.x < 512);
  int tile = isQ ? (int)blockIdx.x : (int)blockIdx.x - 512;
  const float* src = isQ ? q : k;
  int row0 = tile * 128;

  // stage proj frags (coalesced, XOR-swizzled slots)
  for (int i = tid; i < 2048; i += 512){
    int m = i >> 3, c8 = i & 7;
    int rgn = ((m>>5)*4 + (c8>>1))*2 + (c8&1);
    int slot = (m & 31) ^ ((rgn & 7) << 2);
    *(uint4*)(Bp + rgn*512 + slot*16) = *(const uint4*)(pjh + m*64 + c8*8);
  }
  // stage x frags (coalesced float4 -> fp16 hi/lo), per-row sum(x^2)
  #pragma unroll
  for (int it = 0; it < 4; ++it){
    int g = it*512 + tid;
    int row = g >> 4, c4 = g & 15;
    float4 xv = *(const float4*)(src + (size_t)(row0+row)*64 + c4*4);
    _Float16 h0=(_Float16)xv.x, h1=(_Float16)xv.y, h2=(_Float16)xv.z, h3=(_Float16)xv.w;
    float l0 = xv.x-(float)h0, l1 = xv.y-(float)h1, l2 = xv.z-(float)h2, l3 = xv.w-(float)h3;
    int rgn = ((row>>5)*4 + (c4>>2))*2 + ((c4>>1)&1);
    int off = rgn*512 + (((row&31) ^ ((c4>>1)<<2)))*16 + (c4&1)*8;
    uint2 ph; ph.x = (unsigned)h2u(h0)|((unsigned)h2u(h1)<<16);
              ph.y = (unsigned)h2u(h2)|((unsigned)h2u(h3)<<16);
    uint2 pl; pl.x = pk2h(l0,l1); pl.y = pk2h(l2,l3);
    *(uint2*)(Xh + off) = ph;
    *(uint2*)(Xl + off) = pl;
    float ssq = xv.x*xv.x + xv.y*xv.y + xv.z*xv.z + xv.w*xv.w;
    ssq += __shfl_xor(ssq, 1); ssq += __shfl_xor(ssq, 2);
    ssq += __shfl_xor(ssq, 4); ssq += __shfl_xor(ssq, 8);
    if ((tid & 15) == 0) dsm[row] = ssq;
  }
  __syncthreads();

  f16x8 ah[4], al[4];
  #pragma unroll
  for (int ks = 0; ks < 4; ++ks){
    int rgn = (wr*4+ks)*2+half;
    int off = rgn*512 + ((l31 ^ ((2*ks+half)<<2)))*16;
    ah[ks] = *(const f16x8*)(Xh + off);
    al[ks] = *(const f16x8*)(Xl + off);
  }
  f32x16 acc[4];
  #pragma unroll
  for (int ct=0; ct<4; ++ct){
    #pragma unroll
    for (int r=0; r<16; ++r) acc[ct][r] = 0.f;
  }
  #pragma unroll
  for (int ks = 0; ks < 4; ++ks){
    #pragma unroll
    for (int ct=0; ct<4; ++ct){
      int ctg = wc*4 + ct;
      int rgn = (ctg*4+ks)*2+half;
      f16x8 bv = *(const f16x8*)(Bp + rgn*512 + ((l31 ^ ((2*ks+half)<<2)))*16);
      acc[ct] = __builtin_amdgcn_mfma_f32_32x32x16_f16(ah[ks], bv, acc[ct], 0, 0, 0);
      acc[ct] = __builtin_amdgcn_mfma_f32_32x32x16_f16(al[ks], bv, acc[ct], 0, 0, 0);
    }
  }

  // per-row max over this wave's 128 cols
  float rmax[16];
  #pragma unroll
  for (int r=0; r<16; ++r){
    float mx = acc[0][r];
    #pragma unroll
    for (int ct=1; ct<4; ++ct) mx = fmaxf(mx, acc[ct][r]);
    #pragma unroll
    for (int s=1; s<32; s<<=1) mx = fmaxf(mx, __shfl_xor(mx, s));
    rmax[r] = mx;
  }
  if (isQ){
    if (l31 == 0){
      #pragma unroll
      for (int r=0; r<16; ++r)
        rmx[wc*128 + 32*wr + (r&3) + 8*(r>>2) + 4*half] = rmax[r];
    }
  } else {
    float wm = rmax[0];
    #pragma unroll
    for (int r=1; r<16; ++r) wm = fmaxf(wm, rmax[r]);
    wm = fmaxf(wm, __shfl_xor(wm, 32));
    if (lane == 0) wred[w] = wm;
  }
  __syncthreads();

  float lmb = 0.f;
  if (!isQ){
    lmb = wred[0];
    #pragma unroll
    for (int i=1;i<8;++i) lmb = fmaxf(lmb, wred[i]);
    if (tid == 0){
      lmArr[tile] = lmb;
      atomicMax(kmax, enc_f(lmb));
    }
  }
  float dgv[16], stv[16];
  #pragma unroll
  for (int r=0; r<16; ++r){
    int lrow = 32*wr + (r&3) + 8*(r>>2) + 4*half;
    dgv[r] = DIAGC * dsm[lrow];
    stv[r] = isQ ? fmaxf(rmx[lrow], rmx[128+lrow]) : lmb;
  }

  char* ob = sm;   // [128 rows][512B], swizzle ^((row&15)<<4); overwrites Bp/Xh/Xl
  #pragma unroll
  for (int r=0; r<16; ++r){
    int lrow = 32*wr + (r&3) + 8*(r>>2) + 4*half;
    #pragma unroll
    for (int ct=0; ct<4; ++ct){
      int col = wc*128 + ct*32 + l31;
      float e = __expf(acc[ct][r] - dgv[r] - stv[r]);
      float val = isQ ? RATIO*(e + KEPS) : e;
      *(ushort_t*)(ob + lrow*512 + ((col*2) ^ ((lrow&15)<<4))) = f2bf(val);
    }
  }
  __syncthreads();
  ushort_t* dst = (isQ ? qf : kfp) + (size_t)row0*256;
  for (int i = tid; i < 4096; i += 512){
    int row = i >> 5, s = i & 31;
    uint4 d = *(const uint4*)(ob + row*512 + ((s*16) ^ ((row&15)<<4)));
    *(uint4*)(dst + (size_t)row*256 + ((s ^ (row&15)))*8) = d;
  }
}

// K3 (MFMA): per-chunk sums on corrected kf = alpha*kfpre + kappa (applied at staging).
__launch_bounds__(256)
__global__ void k_chunk(const ushort_t* __restrict__ kfp, const float* __restrict__ v,
                        float* __restrict__ Zl, float* __restrict__ Sl,
                        const float* __restrict__ lmArr, const unsigned* __restrict__ kmax){
  extern __shared__ char sm[];
  char* kT = sm;            // [256 m][256 B]  (c 0..127 bf16)
  char* vT = sm + 65536;    // [64 e][256 B]
  int tid = threadIdx.x;
  int w   = tid >> 6;
  int lane= tid & 63;
  int l31 = lane & 31;
  int half= lane >> 5;
  int bh = blockIdx.x >> 5, j = blockIdx.x & 31;
  int row0 = bh*4096 + j*128;
  int cb = bh*32 + j;

  float gmv = dec_f(*kmax);
  float alpha = RATIO * __expf(lmArr[cb] - gmv);

  {
    const ushort_t* kp = kfp + (size_t)row0*256 + tid;
    char* krow = kT + tid*256;
    int swz = (tid & 15) << 4;
    #pragma unroll 16
    for (int c=0; c<128; ++c){
      float val = fmaf(alpha, bf2f(kp[(size_t)c*256]), KAPPA);
      *(ushort_t*)(krow + ((c*2) ^ swz)) = f2bf(val);
    }
  }
  {
    int e = tid & 63; int c0 = tid >> 6;
    char* vrow = vT + e*256;
    int swz = (e & 15) << 4;
    #pragma unroll 8
    for (int u=0; u<32; ++u){
      int c = c0 + u*4;
      float vv = v[(size_t)(row0+c)*64 + e];
      *(ushort_t*)(vrow + ((c*2) ^ swz)) = f2bf(vv);
    }
  }
  __syncthreads();

  f32x16 acc[2][2];
  f32x16 accz[2];
  #pragma unroll
  for (int a=0;a<2;++a){
    #pragma unroll
    for (int b=0;b<2;++b){
      #pragma unroll
      for (int r=0;r<16;++r) acc[a][b][r]=0.f;
    }
    #pragma unroll
    for (int r=0;r<16;++r) accz[a][r]=0.f;
  }
  bf16x8 onesf;
  #pragma unroll
  for (int i=0;i<8;++i) onesf[i] = (l31==0) ? (short)0x3F80 : (short)0;

  #pragma unroll
  for (int ks=0; ks<8; ++ks){
    int koff = ks*32 + half*16;
    bf16x8 af[2], bf[2];
    #pragma unroll
    for (int mt=0; mt<2; ++mt){
      int m = (2*w + mt)*32 + l31;
      af[mt] = *(const bf16x8*)(kT + m*256 + (koff ^ ((m&15)<<4)));
    }
    #pragma unroll
    for (int et=0; et<2; ++et){
      int e = et*32 + l31;
      bf[et] = *(const bf16x8*)(vT + e*256 + (koff ^ ((e&15)<<4)));
    }
    #pragma unroll
    for (int mt=0; mt<2; ++mt){
      accz[mt] = __builtin_amdgcn_mfma_f32_32x32x16_bf16(af[mt], onesf, accz[mt], 0, 0, 0);
      #pragma unroll
      for (int et=0; et<2; ++et)
        acc[mt][et] = __builtin_amdgcn_mfma_f32_32x32x16_bf16(af[mt], bf[et], acc[mt][et], 0, 0, 0);
    }
  }

  #pragma unroll
  for (int mt=0; mt<2; ++mt){
    #pragma unroll
    for (int r=0; r<16; ++r){
      int m = (2*w + mt)*32 + (r&3) + 8*(r>>2) + 4*half;
      #pragma unroll
      for (int et=0; et<2; ++et){
        int e = et*32 + l31;
        Sl[(size_t)cb*16384 + (size_t)m*64 + e] = acc[mt][et][r];
      }
    }
  }
  if (l31 == 0){
    #pragma unroll
    for (int mt=0; mt<2; ++mt){
      #pragma unroll
      for (int r=0; r<16; ++r){
        int m = (2*w + mt)*32 + (r&3) + 8*(r>>2) + 4*half;
        Zl[(size_t)cb*256 + m] = accz[mt][r];
      }
    }
  }
}

// K4: parallel exclusive scan over 32 chunks. Zl: excl in place + outZ.
// S: read Sl fp32, write S0b (bf16 exclusive, [cb][m][e]) + outS (fp32 inclusive).
__launch_bounds__(256)
__global__ void k_scan(float* __restrict__ Zl, const float* __restrict__ Sl,
                       ushort_t* __restrict__ S0b,
                       float* __restrict__ outZ, float* __restrict__ outS){
  int t = threadIdx.x;
  int bh = blockIdx.x / 65;
  int s  = blockIdx.x % 65;
  if (s == 64){
    size_t base = (size_t)(bh*32)*256 + t;
    float rz = 0.f;
    #pragma unroll
    for (int j0=0;j0<32;j0+=8){
      float x[8];
      #pragma unroll
      for (int u=0;u<8;++u) x[u] = Zl[base + (size_t)(j0+u)*256];
      #pragma unroll
      for (int u=0;u<8;++u){ Zl[base + (size_t)(j0+u)*256] = rz; rz += x[u]; }
    }
    outZ[(size_t)bh*256 + t] = rz;
  } else {
    size_t base = (size_t)(bh*32)*16384 + (size_t)s*256 + t;
    float rs = 0.f;
    #pragma unroll
    for (int j0=0;j0<32;j0+=8){
      float x[8];
      #pragma unroll
      for (int u=0;u<8;++u) x[u] = Sl[base + (size_t)(j0+u)*16384];
      #pragma unroll
      for (int u=0;u<8;++u){
        S0b[(size_t)(bh*32 + j0+u)*16384 + (size_t)s*256 + t] = f2bf(rs);
        rs += x[u];
      }
    }
    outS[(size_t)bh*16384 + (size_t)s*256 + t] = rs;
  }
}

// K5 (MFMA): per-chunk output; qz fused into qt staging; merged m-loop does
// A-part (qf*kf^T) and S0-part (qf*S0) off one staging; then A*v; divide.
__launch_bounds__(256)
__global__ void k_out(const ushort_t* __restrict__ qf, const ushort_t* __restrict__ kfp,
                      const float* __restrict__ v, const ushort_t* __restrict__ S0b,
                      const float* __restrict__ Zp, float* __restrict__ outO,
                      const float* __restrict__ lmArr, const unsigned* __restrict__ kmax){
  extern __shared__ char smc[];
  char* Ab  = smc;                  // [128][256B] bf16, swizzle ^((r&15)<<4)
  char* qtb = smc + 32768;          // [128][128B] bf16, swizzle ^((r&7)<<4)
  char* ktb = smc + 49152;          // [128][128B]
  char* s0t = smc + 65536;          // [64 e][128B], swizzle ^(((e&7)^((e>>3)&7))<<4)
  float* z0  = (float*)(smc + 73728);   // [256]
  float* qzl = (float*)(smc + 74752);   // [128]
  float* rsum= (float*)(smc + 75264);   // [128]

  int tid = threadIdx.x;
  int w   = tid >> 6;
  int lane= tid & 63;
  int l31 = lane & 31;
  int half= lane >> 5;
  int arow= 32*w + l31;
  int bh = blockIdx.x >> 5, j = blockIdx.x & 31;
  int row0 = bh*4096 + j*128;
  size_t qbase = (size_t)row0*256;
  int pb = bh*32 + j;

  float gmv = dec_f(*kmax);
  float alpha = RATIO * __expf(lmArr[pb] - gmv);

  z0[tid] = Zp[(size_t)pb*256 + tid] + AEPS;
  float qzp = 0.f;

  f32x16 acc[4];
  f32x16 acc2[2];
  #pragma unroll
  for (int ct=0;ct<4;++ct){
    #pragma unroll
    for (int r=0;r<16;++r) acc[ct][r] = 0.f;
  }
  #pragma unroll
  for (int et=0;et<2;++et){
    #pragma unroll
    for (int r=0;r<16;++r) acc2[et][r] = 0.f;
  }

  for (int m0=0;m0<256;m0+=64){
    __syncthreads();
    #pragma unroll
    for (int u=0;u<4;++u){
      int ci = tid*4+u; int rr = ci>>3, c8 = ci&7;
      int sw = (c8*16) ^ ((rr&7)<<4);
      uint4 rq = *(const uint4*)(qf + qbase + (size_t)rr*256 + m0 + c8*8);
      *(uint4*)(qtb + rr*128 + sw) = rq;
      float4 za = *(const float4*)&z0[m0 + c8*8];
      float4 zb = *(const float4*)&z0[m0 + c8*8 + 4];
      qzp += bf2f((ushort_t)(rq.x&0xffffu))*za.x + bf2f((ushort_t)(rq.x>>16))*za.y
           + bf2f((ushort_t)(rq.y&0xffffu))*za.z + bf2f((ushort_t)(rq.y>>16))*za.w
           + bf2f((ushort_t)(rq.z&0xffffu))*zb.x + bf2f((ushort_t)(rq.z>>16))*zb.y
           + bf2f((ushort_t)(rq.w&0xffffu))*zb.z + bf2f((ushort_t)(rq.w>>16))*zb.w;
      uint4 rk = *(const uint4*)(kfp + qbase + (size_t)rr*256 + m0 + c8*8);
      uint4 ck; ck.x = cvt2(rk.x, alpha); ck.y = cvt2(rk.y, alpha);
                ck.z = cvt2(rk.z, alpha); ck.w = cvt2(rk.w, alpha);
      *(uint4*)(ktb + rr*128 + sw) = ck;
    }
    #pragma unroll
    for (int u=0;u<2;++u){
      int idx = u*256 + tid; int mm = idx>>3, c8 = idx&7;
      uint4 sv = *(const uint4*)(S0b + (size_t)pb*16384 + (size_t)(m0+mm)*64 + c8*8);
      unsigned wds[4] = {sv.x, sv.y, sv.z, sv.w};
      #pragma unroll
      for (int jj=0;jj<4;++jj){
        int e0 = c8*8 + jj*2;
        int e1 = e0 + 1;
        int sw0 = ((e0&7) ^ ((e0>>3)&7)) << 4;
        int sw1 = ((e1&7) ^ ((e1>>3)&7)) << 4;
        *(ushort_t*)(s0t + e0*128 + ((mm*2) ^ sw0)) = (ushort_t)(wds[jj] & 0xffffu);
        *(ushort_t*)(s0t + e1*128 + ((mm*2) ^ sw1)) = (ushort_t)(wds[jj] >> 16);
      }
    }
    __syncthreads();
    #pragma unroll
    for (int ks=0;ks<4;++ks){
      bf16x8 af = *(const bf16x8*)(qtb + arow*128 + ((ks*32 + half*16) ^ ((arow&7)<<4)));
      #pragma unroll
      for (int et=0;et<2;++et){
        int er = et*32 + l31;
        int sw = ((er&7) ^ ((er>>3)&7)) << 4;
        bf16x8 bS = *(const bf16x8*)(s0t + er*128 + ((ks*32 + half*16) ^ sw));
        acc2[et] = __builtin_amdgcn_mfma_f32_32x32x16_bf16(af, bS, acc2[et], 0, 0, 0);
      }
      #pragma unroll
      for (int ct=0;ct<4;++ct){
        if (ct <= w){
          int br = ct*32 + l31;
          bf16x8 bfv = *(const bf16x8*)(ktb + br*128 + ((ks*32 + half*16) ^ ((br&7)<<4)));
          acc[ct] = __builtin_amdgcn_mfma_f32_32x32x16_bf16(af, bfv, acc[ct], 0, 0, 0);
        }
      }
    }
  }

  // qz combine (threads tid, tid^1 share row tid>>1)
  qzp += __shfl_xor(qzp, 1);
  if ((tid & 1) == 0) qzl[tid>>1] = qzp;

  // A: mask, bf16 -> Ab, exact fp32 rowsums
  float p[16];
  #pragma unroll
  for (int r=0;r<16;++r) p[r]=0.f;
  #pragma unroll
  for (int ct=0;ct<4;++ct){
    #pragma unroll
    for (int r=0;r<16;++r){
      int grow = 32*w + (r&3) + 8*(r>>2) + 4*half;
      int col  = ct*32 + l31;
      float m = (col <= grow) ? acc[ct][r] : 0.f;
      p[r] += m;
      *(ushort_t*)(Ab + grow*256 + ((col*2) ^ ((grow&15)<<4))) = f2bf(m);
    }
  }
  #pragma unroll
  for (int s=1;s<32;s<<=1){
    #pragma unroll
    for (int r=0;r<16;++r) p[r] += __shfl_xor(p[r], s);
  }
  if (l31 == 0){
    #pragma unroll
    for (int r=0;r<16;++r) rsum[32*w + (r&3) + 8*(r>>2) + 4*half] = p[r];
  }
  __syncthreads();

  // A*v over 2 K=64 tiles (v bf16-staged into s0t region)
  for (int kt=0; kt<2; ++kt){
    #pragma unroll
    for (int u=0;u<4;++u){
      int idx = tid*4+u; int rr = idx>>4, c4 = idx&15;
      float4 vv = *(const float4*)&v[(size_t)(row0 + kt*64 + rr)*64 + c4*4];
      float vals[4] = {vv.x, vv.y, vv.z, vv.w};
      #pragma unroll
      for (int jj=0;jj<4;++jj){
        int e = c4*4 + jj;
        int sw = ((e&7) ^ ((e>>3)&7)) << 4;
        *(ushort_t*)(s0t + e*128 + ((rr*2) ^ sw)) = f2bf(vals[jj]);
      }
    }
    __syncthreads();
    #pragma unroll
    for (int ks=0;ks<4;++ks){
      if (kt*64 + ks*16 <= 32*w + 31){   // wave-uniform: A zero above diagonal
        bf16x8 af = *(const bf16x8*)(Ab + arow*256 + ((kt*128 + ks*32 + half*16) ^ ((arow&15)<<4)));
        #pragma unroll
        for (int et=0;et<2;++et){
          int er = et*32 + l31;
          int sw = ((er&7) ^ ((er>>3)&7)) << 4;
          bf16x8 bfv = *(const bf16x8*)(s0t + er*128 + ((ks*32 + half*16) ^ sw));
          acc2[et] = __builtin_amdgcn_mfma_f32_32x32x16_bf16(af, bfv, acc2[et], 0, 0, 0);
        }
      }
    }
    __syncthreads();
  }

  if (tid < 128) rsum[tid] = 1.0f / (rsum[tid] + qzl[tid]);
  __syncthreads();
  float dvv[16];
  #pragma unroll
  for (int r=0;r<16;++r) dvv[r] = rsum[32*w + (r&3) + 8*(r>>2) + 4*half];
  #pragma unroll
  for (int et=0;et<2;++et){
    #pragma unroll
    for (int r=0;r<16;++r){
      int qrow = 32*w + (r&3) + 8*(r>>2) + 4*half;
      int e = et*32 + l31;
      outO[(size_t)(row0+qrow)*64 + e] = acc2[et][r] * dvv[r];
    }
  }
}

extern "C" void kernel_launch(void* const* d_in, const int* in_sizes, int n_in,
                              void* d_out, int out_size, void* d_ws, size_t ws_size,
                              hipStream_t stream){
  (void)in_sizes; (void)n_in; (void)out_size; (void)ws_size;
  const float* q    = (const float*)d_in[0];
  const float* k    = (const float*)d_in[1];
  const float* v    = (const float*)d_in[2];
  const float* proj = (const float*)d_in[3];

  char* ws = (char*)d_ws;
  unsigned* kmax = (unsigned*)ws;                                   // @0
  float*    lmA  = (float*)(ws + 256);                              // 2048 B
  ushort_t* pjh  = (ushort_t*)(ws + 4096);                          // 32768 B
  ushort_t* qf   = (ushort_t*)(ws + 65792);                         // 33554432 B
  ushort_t* kfp  = (ushort_t*)(ws + 65792 + 33554432);              // 33554432 B
  float*    Zl   = (float*)(ws + 65792 + 67108864);                 // 524288 B
  float*    Sl   = (float*)(ws + 65792 + 67108864 + 524288);        // 33554432 B
  ushort_t* S0b  = (ushort_t*)(ws + 65792 + 67108864 + 524288 + 33554432); // 16777216 B

  float* outO = (float*)d_out;
  float* outZ = outO + (size_t)2*8*4096*64;
  float* outS = outZ + 2*8*256;

  hipFuncSetAttribute((const void*)k_feat,  hipFuncAttributeMaxDynamicSharedMemorySize, 67104);
  hipFuncSetAttribute((const void*)k_chunk, hipFuncAttributeMaxDynamicSharedMemorySize, 81920);
  hipFuncSetAttribute((const void*)k_out,   hipFuncAttributeMaxDynamicSharedMemorySize, 75776);

  k_prep <<<1,      256, 0, stream>>>(proj, pjh, kmax);
  k_feat <<<1024,   512, 67104, stream>>>(q, k, pjh, qf, kfp, kmax, lmA);
  k_chunk<<<512,    256, 81920, stream>>>(kfp, v, Zl, Sl, lmA, kmax);
  k_scan <<<16*65,  256, 0, stream>>>(Zl, Sl, S0b, outZ, outS);
  k_out  <<<512,    256, 75776, stream>>>(qf, kfp, v, S0b, Zl, outO, lmA, kmax);
}